// Round 1
// baseline (1738.428 us; speedup 1.0000x reference)
//
#include <hip/hip_runtime.h>
#include <math.h>

#define NN 50000      // nodes
#define NE 800000     // edges
#define NG 128        // graphs
#define HD 128        // H*D
#define NH 4          // heads
#define ND 32         // dim per head
#define NC 10         // classes
#define NEG_SLOPE 0.2f

// ---- order-preserving float <-> unsigned encoding for atomicMax ----
__device__ __forceinline__ unsigned enc_f(float f) {
    int b = __float_as_int(f);
    return (unsigned)b ^ ((unsigned)(b >> 31) | 0x80000000u);
}
__device__ __forceinline__ float dec_f(unsigned u) {
    int b = (u & 0x80000000u) ? (int)(u ^ 0x80000000u) : (int)~u;
    return __int_as_float(b);
}

// ---- GEMM (x[N,128] @ W[128,128]) fused with el/er attention logits ----
#define RPB 64
__global__ __launch_bounds__(128) void k_gemm_attn(
    const float* __restrict__ X, const float* __restrict__ W,
    const float* __restrict__ al, const float* __restrict__ ar,
    float* __restrict__ Z, float* __restrict__ el, float* __restrict__ er)
{
    __shared__ float Wl[HD * HD];   // 64 KiB
    __shared__ float xs[HD];
    const int col = threadIdx.x;            // 0..127 = h*32+d
    for (int i = col; i < HD * HD; i += 128) Wl[i] = W[i];
    const int h = col >> 5;
    const float a_l = al[col];
    const float a_r = ar[col];
    __syncthreads();
    const int row0 = blockIdx.x * RPB;
    for (int r = 0; r < RPB; ++r) {
        const int row = row0 + r;
        if (row >= NN) break;               // uniform across block
        xs[col] = X[row * HD + col];
        __syncthreads();
        float acc = 0.f;
        #pragma unroll
        for (int k = 0; k < HD; ++k) acc = fmaf(xs[k], Wl[k * HD + col], acc);
        Z[row * HD + col] = acc;
        // el[row,h] = sum_d z*al ; reduce over the 32 lanes of this head
        float pl = acc * a_l, pr = acc * a_r;
        #pragma unroll
        for (int off = 16; off >= 1; off >>= 1) {
            pl += __shfl_xor(pl, off);
            pr += __shfl_xor(pr, off);
        }
        if ((col & 31) == 0) { el[row * NH + h] = pl; er[row * NH + h] = pr; }
        __syncthreads();                    // xs reused next row
    }
}

__global__ void k_init_emax(unsigned* __restrict__ emax) {
    int t = blockIdx.x * blockDim.x + threadIdx.x;
    if (t < NN * NH) emax[t] = 0x007FFFFFu;  // enc(-inf)
}

// ---- pass 1: segment max over incoming edges of dst ----
__global__ void k_edge_max(const int* __restrict__ src, const int* __restrict__ dst,
                           const float* __restrict__ el, const float* __restrict__ er,
                           unsigned* __restrict__ emax)
{
    int t = blockIdx.x * blockDim.x + threadIdx.x;
    if (t >= NE * NH) return;
    int e = t >> 2, h = t & 3;
    int s = src[e], d = dst[e];
    float x = el[s * NH + h] + er[d * NH + h];
    x = x >= 0.f ? x : NEG_SLOPE * x;
    atomicMax(&emax[d * NH + h], enc_f(x));
}

// ---- pass 2: ee = exp(e - emax[dst]); num[dst] += z[src]*ee; denom[dst,h] += ee ----
__global__ void k_edge_accum(const int* __restrict__ src, const int* __restrict__ dst,
                             const float* __restrict__ el, const float* __restrict__ er,
                             const unsigned* __restrict__ emax, const float* __restrict__ Z,
                             float* __restrict__ num, float* __restrict__ denom)
{
    long long t = (long long)blockIdx.x * blockDim.x + threadIdx.x;
    if (t >= (long long)NE * HD) return;
    int e = (int)(t >> 7), c = (int)(t & 127), h = c >> 5;
    int s = src[e], d = dst[e];
    float x = el[s * NH + h] + er[d * NH + h];
    x = x >= 0.f ? x : NEG_SLOPE * x;
    float m = dec_f(emax[d * NH + h]);
    float ee = __expf(x - m);
    atomicAdd(&num[d * HD + c], Z[s * HD + c] * ee);
    if ((c & 31) == 0) atomicAdd(&denom[d * NH + h], ee);
}

// ---- finalize: x = relu(num/denom + b) ----
__global__ void k_node_finalize(const float* __restrict__ num, const float* __restrict__ denom,
                                const float* __restrict__ b, float* __restrict__ X)
{
    int t = blockIdx.x * blockDim.x + threadIdx.x;
    if (t >= NN * HD) return;
    int n = t >> 7, c = t & 127, h = c >> 5;
    float den = denom[n * NH + h];
    float v = (den > 0.f ? num[t] / den : 0.f) + b[c];
    X[t] = v > 0.f ? v : 0.f;
}

// ---- mean pooling by graph ----
__global__ void k_pool(const float* __restrict__ X, const int* __restrict__ gid,
                       float* __restrict__ gsum, float* __restrict__ gcnt)
{
    int t = blockIdx.x * blockDim.x + threadIdx.x;
    if (t >= NN * HD) return;
    int n = t >> 7, c = t & 127;
    int g = gid[n];
    atomicAdd(&gsum[g * HD + c], X[t]);
    if (c == 0) atomicAdd(&gcnt[g], 1.0f);
}

// ---- classifier: out[g,c] = bc[c] + sum_k (gsum[g,k]/max(cnt,1)) * Wc[k,c] ----
__global__ void k_classifier(const float* __restrict__ gsum, const float* __restrict__ gcnt,
                             const float* __restrict__ Wc, const float* __restrict__ bc,
                             float* __restrict__ out)
{
    int t = blockIdx.x * blockDim.x + threadIdx.x;
    if (t >= NG * NC) return;
    int g = t / NC, c = t % NC;
    float inv = 1.f / fmaxf(gcnt[g], 1.f);
    float acc = bc[c];
    #pragma unroll
    for (int k = 0; k < HD; ++k)
        acc = fmaf(gsum[g * HD + k] * inv, Wc[k * NC + c], acc);
    out[t] = acc;
}

extern "C" void kernel_launch(void* const* d_in, const int* in_sizes, int n_in,
                              void* d_out, int out_size, void* d_ws, size_t ws_size,
                              hipStream_t stream) {
    const float* h    = (const float*)d_in[0];
    const int*   src  = (const int*)  d_in[1];
    const int*   dst  = (const int*)  d_in[2];
    const int*   gid  = (const int*)  d_in[3];
    const float* W1   = (const float*)d_in[4];
    const float* al1  = (const float*)d_in[5];
    const float* ar1  = (const float*)d_in[6];
    const float* b1   = (const float*)d_in[7];
    const float* W2   = (const float*)d_in[8];
    const float* al2  = (const float*)d_in[9];
    const float* ar2  = (const float*)d_in[10];
    const float* b2   = (const float*)d_in[11];
    const float* Wc   = (const float*)d_in[12];
    const float* bc   = (const float*)d_in[13];
    float* out = (float*)d_out;

    char* w = (char*)d_ws;
    float*    z     = (float*)w;            w += (size_t)NN * HD * 4;
    float*    xb    = (float*)w;            w += (size_t)NN * HD * 4;
    float*    num   = (float*)w;            w += (size_t)NN * HD * 4;
    float*    el    = (float*)w;            w += (size_t)NN * NH * 4;
    float*    er    = (float*)w;            w += (size_t)NN * NH * 4;
    float*    denom = (float*)w;            w += (size_t)NN * NH * 4;
    unsigned* emax  = (unsigned*)w;         w += (size_t)NN * NH * 4;
    float*    gsum  = (float*)w;            w += (size_t)NG * HD * 4;
    float*    gcnt  = (float*)w;            w += (size_t)NG * 4;

    const int TB = 256;
    const int gN4   = (NN * NH + TB - 1) / TB;
    const int gEH   = (NE * NH + TB - 1) / TB;
    const long long ec = (long long)NE * HD;
    const int gEC   = (int)((ec + TB - 1) / TB);
    const int gNF   = (NN * HD + TB - 1) / TB;
    const int gGemm = (NN + RPB - 1) / RPB;

    // ---------------- layer 1 ----------------
    k_gemm_attn<<<gGemm, 128, 0, stream>>>(h, W1, al1, ar1, z, el, er);
    hipMemsetAsync(num, 0, (size_t)NN * HD * 4, stream);
    hipMemsetAsync(denom, 0, (size_t)NN * NH * 4, stream);
    k_init_emax<<<gN4, TB, 0, stream>>>(emax);
    k_edge_max<<<gEH, TB, 0, stream>>>(src, dst, el, er, emax);
    k_edge_accum<<<gEC, TB, 0, stream>>>(src, dst, el, er, emax, z, num, denom);
    k_node_finalize<<<gNF, TB, 0, stream>>>(num, denom, b1, xb);

    // ---------------- layer 2 ----------------
    k_gemm_attn<<<gGemm, 128, 0, stream>>>(xb, W2, al2, ar2, z, el, er);
    hipMemsetAsync(num, 0, (size_t)NN * HD * 4, stream);
    hipMemsetAsync(denom, 0, (size_t)NN * NH * 4, stream);
    k_init_emax<<<gN4, TB, 0, stream>>>(emax);
    k_edge_max<<<gEH, TB, 0, stream>>>(src, dst, el, er, emax);
    k_edge_accum<<<gEC, TB, 0, stream>>>(src, dst, el, er, emax, z, num, denom);
    k_node_finalize<<<gNF, TB, 0, stream>>>(num, denom, b2, z);   // final node feats -> z

    // ---------------- pooling + classifier ----------------
    hipMemsetAsync(gsum, 0, (size_t)NG * HD * 4, stream);
    hipMemsetAsync(gcnt, 0, (size_t)NG * 4, stream);
    k_pool<<<gNF, TB, 0, stream>>>(z, gid, gsum, gcnt);
    k_classifier<<<(NG * NC + 127) / 128, 128, 0, stream>>>(gsum, gcnt, Wc, bc, out);
}

// Round 2
// 1071.292 us; speedup vs baseline: 1.6227x; 1.6227x over previous
//
#include <hip/hip_runtime.h>
#include <math.h>

#define NN 50000      // nodes
#define NE 800000     // edges
#define NG 128        // graphs
#define HD 128        // H*D
#define NH 4          // heads
#define NC 10         // classes
#define NEG_SLOPE 0.2f

// ---- GEMM (x[N,128] @ W[128,128]) fused with el/er attention logits ----
#define RPB 64
__global__ __launch_bounds__(128) void k_gemm_attn(
    const float* __restrict__ X, const float* __restrict__ W,
    const float* __restrict__ al, const float* __restrict__ ar,
    float* __restrict__ Z, float* __restrict__ el, float* __restrict__ er)
{
    __shared__ float Wl[HD * HD];   // 64 KiB
    __shared__ float xs[HD];
    const int col = threadIdx.x;            // 0..127 = h*32+d
    for (int i = col; i < HD * HD; i += 128) Wl[i] = W[i];
    const int h = col >> 5;
    const float a_l = al[col];
    const float a_r = ar[col];
    __syncthreads();
    const int row0 = blockIdx.x * RPB;
    for (int r = 0; r < RPB; ++r) {
        const int row = row0 + r;
        if (row >= NN) break;               // uniform across block
        xs[col] = X[row * HD + col];
        __syncthreads();
        float acc = 0.f;
        #pragma unroll
        for (int k = 0; k < HD; ++k) acc = fmaf(xs[k], Wl[k * HD + col], acc);
        Z[row * HD + col] = acc;
        float pl = acc * a_l, pr = acc * a_r;
        #pragma unroll
        for (int off = 16; off >= 1; off >>= 1) {
            pl += __shfl_xor(pl, off);
            pr += __shfl_xor(pr, off);
        }
        if ((col & 31) == 0) { el[row * NH + h] = pl; er[row * NH + h] = pr; }
        __syncthreads();                    // xs reused next row
    }
}

// ---------------- CSR build (dst-sorted edge list), once per call ----------------
__global__ void k_deg(const int* __restrict__ dst, int* __restrict__ deg) {
    int t = blockIdx.x * blockDim.x + threadIdx.x;
    if (t < NE) atomicAdd(&deg[dst[t]], 1);
}

// single-block exclusive scan deg[NN] -> offs[NN+1]; also seeds cursor = offs
__global__ __launch_bounds__(1024) void k_scan(const int* __restrict__ deg,
                                               int* __restrict__ offs,
                                               int* __restrict__ cursor)
{
    __shared__ int wsum[16];
    __shared__ int sbase;
    const int tid = threadIdx.x, lane = tid & 63, w = tid >> 6;
    if (tid == 0) sbase = 0;
    __syncthreads();
    for (int start = 0; start < NN; start += 1024) {
        int i = start + tid;
        int v = (i < NN) ? deg[i] : 0;
        int x = v;
        #pragma unroll
        for (int off = 1; off < 64; off <<= 1) {
            int t = __shfl_up(x, off);
            if (lane >= off) x += t;
        }
        if (lane == 63) wsum[w] = x;
        __syncthreads();
        if (w == 0 && lane < 16) {
            int t = wsum[lane];
            #pragma unroll
            for (int off = 1; off < 16; off <<= 1) {
                int u = __shfl_up(t, off);
                if (lane >= off) t += u;
            }
            wsum[lane] = t;   // inclusive scan of wave sums
        }
        __syncthreads();
        int wbase = (w == 0) ? 0 : wsum[w - 1];
        int excl = sbase + wbase + x - v;
        if (i < NN) { offs[i] = excl; cursor[i] = excl; }
        __syncthreads();                      // all reads of sbase/wsum done
        if (tid == 0) sbase += wsum[15];
        __syncthreads();
    }
    if (tid == 0) offs[NN] = sbase;           // == NE
}

__global__ void k_scatter(const int* __restrict__ src, const int* __restrict__ dst,
                          int* __restrict__ cursor, int* __restrict__ csrc) {
    int t = blockIdx.x * blockDim.x + threadIdx.x;
    if (t < NE) {
        int pos = atomicAdd(&cursor[dst[t]], 1);
        csrc[pos] = src[t];
    }
}

// ---- fused edge softmax + aggregate + finalize: one wave per dst node ----
// lane owns channels c0=2*lane, c0+1 (same head h=lane>>4) -> one exp chain/lane
__global__ __launch_bounds__(256) void k_edge_gat(
    const int* __restrict__ offs, const int* __restrict__ csrc,
    const float* __restrict__ el, const float* __restrict__ er,
    const float* __restrict__ Z, const float* __restrict__ b,
    float* __restrict__ X)
{
    int wid = (int)((blockIdx.x * (unsigned)blockDim.x + threadIdx.x) >> 6);
    int lane = threadIdx.x & 63;
    if (wid >= NN) return;
    const int d = wid;
    const int beg = offs[d], end = offs[d + 1];
    const int c0 = lane * 2;
    const int h = lane >> 4;
    const float erd = er[d * NH + h];
    const float2 bb = *(const float2*)&b[c0];

    float m = -INFINITY, sden = 0.f, a0 = 0.f, a1 = 0.f;
    for (int i = beg; i < end; ++i) {
        int s = csrc[i];
        float2 z = *(const float2*)&Z[(size_t)s * HD + c0];
        float e = el[s * NH + h] + erd;
        e = e >= 0.f ? e : NEG_SLOPE * e;
        float nm = fmaxf(m, e);
        float r = __expf(m - nm);      // 0 on first edge (m=-inf)
        float p = __expf(e - nm);
        sden = sden * r + p;
        a0 = a0 * r + z.x * p;
        a1 = a1 * r + z.y * p;
        m = nm;
    }
    float inv = (end > beg) ? 1.f / sden : 0.f;
    float v0 = a0 * inv + bb.x;
    float v1 = a1 * inv + bb.y;
    float2 o;
    o.x = v0 > 0.f ? v0 : 0.f;
    o.y = v1 > 0.f ? v1 : 0.f;
    *(float2*)&X[(size_t)d * HD + c0] = o;
}

// ---- mean pooling by graph ----
__global__ void k_pool(const float* __restrict__ X, const int* __restrict__ gid,
                       float* __restrict__ gsum, float* __restrict__ gcnt)
{
    int t = blockIdx.x * blockDim.x + threadIdx.x;
    if (t >= NN * HD) return;
    int n = t >> 7, c = t & 127;
    int g = gid[n];
    atomicAdd(&gsum[g * HD + c], X[t]);
    if (c == 0) atomicAdd(&gcnt[g], 1.0f);
}

// ---- classifier ----
__global__ void k_classifier(const float* __restrict__ gsum, const float* __restrict__ gcnt,
                             const float* __restrict__ Wc, const float* __restrict__ bc,
                             float* __restrict__ out)
{
    int t = blockIdx.x * blockDim.x + threadIdx.x;
    if (t >= NG * NC) return;
    int g = t / NC, c = t % NC;
    float inv = 1.f / fmaxf(gcnt[g], 1.f);
    float acc = bc[c];
    #pragma unroll
    for (int k = 0; k < HD; ++k)
        acc = fmaf(gsum[g * HD + k] * inv, Wc[k * NC + c], acc);
    out[t] = acc;
}

extern "C" void kernel_launch(void* const* d_in, const int* in_sizes, int n_in,
                              void* d_out, int out_size, void* d_ws, size_t ws_size,
                              hipStream_t stream) {
    const float* h    = (const float*)d_in[0];
    const int*   src  = (const int*)  d_in[1];
    const int*   dst  = (const int*)  d_in[2];
    const int*   gid  = (const int*)  d_in[3];
    const float* W1   = (const float*)d_in[4];
    const float* al1  = (const float*)d_in[5];
    const float* ar1  = (const float*)d_in[6];
    const float* b1   = (const float*)d_in[7];
    const float* W2   = (const float*)d_in[8];
    const float* al2  = (const float*)d_in[9];
    const float* ar2  = (const float*)d_in[10];
    const float* b2   = (const float*)d_in[11];
    const float* Wc   = (const float*)d_in[12];
    const float* bc   = (const float*)d_in[13];
    float* out = (float*)d_out;

    char* w = (char*)d_ws;
    float* z    = (float*)w;  w += (size_t)NN * HD * 4;   // 25.6 MB
    float* xb   = (float*)w;  w += (size_t)NN * HD * 4;   // 25.6 MB
    float* el   = (float*)w;  w += (size_t)NN * NH * 4;
    float* er   = (float*)w;  w += (size_t)NN * NH * 4;
    int*   deg  = (int*)w;    w += (size_t)NN * 4;
    int*   offs = (int*)w;    w += (size_t)(NN + 1) * 4;
    int*   curs = (int*)w;    w += (size_t)NN * 4;
    int*   csrc = (int*)w;    w += (size_t)NE * 4;        // 3.2 MB
    float* gsum = (float*)w;  w += (size_t)NG * HD * 4;
    float* gcnt = (float*)w;  w += (size_t)NG * 4;

    const int TB = 256;
    const int gE    = (NE + TB - 1) / TB;
    const int gNF   = (NN * HD + TB - 1) / TB;
    const int gGemm = (NN + RPB - 1) / RPB;
    const int gEdge = (NN * 64 + TB - 1) / TB;   // one wave per dst

    // ---------------- CSR build (dst constant across layers) ----------------
    hipMemsetAsync(deg, 0, (size_t)NN * 4, stream);
    k_deg<<<gE, TB, 0, stream>>>(dst, deg);
    k_scan<<<1, 1024, 0, stream>>>(deg, offs, curs);
    k_scatter<<<gE, TB, 0, stream>>>(src, dst, curs, csrc);

    // ---------------- layer 1 ----------------
    k_gemm_attn<<<gGemm, 128, 0, stream>>>(h, W1, al1, ar1, z, el, er);
    k_edge_gat<<<gEdge, TB, 0, stream>>>(offs, csrc, el, er, z, b1, xb);

    // ---------------- layer 2 ----------------
    k_gemm_attn<<<gGemm, 128, 0, stream>>>(xb, W2, al2, ar2, z, el, er);
    k_edge_gat<<<gEdge, TB, 0, stream>>>(offs, csrc, el, er, z, b2, xb);

    // ---------------- pooling + classifier ----------------
    hipMemsetAsync(gsum, 0, (size_t)NG * HD * 4, stream);
    hipMemsetAsync(gcnt, 0, (size_t)NG * 4, stream);
    k_pool<<<gNF, TB, 0, stream>>>(xb, gid, gsum, gcnt);
    k_classifier<<<(NG * NC + 127) / 128, 128, 0, stream>>>(gsum, gcnt, Wc, bc, out);
}

// Round 3
// 754.750 us; speedup vs baseline: 2.3033x; 1.4194x over previous
//
#include <hip/hip_runtime.h>
#include <math.h>

#define NN 50000      // nodes
#define NE 800000     // edges
#define NG 128        // graphs
#define HD 128        // H*D
#define NH 4          // heads
#define NC 10         // classes
#define NEG_SLOPE 0.2f

// ---- GEMM (x[N,128] @ W[128,128]) fused with el/er attention logits ----
// 256 threads: two 128-thread row-groups share the 64 KiB W tile -> 8 waves/CU
#define RPB 64
__global__ __launch_bounds__(256) void k_gemm_attn(
    const float* __restrict__ X, const float* __restrict__ W,
    const float* __restrict__ al, const float* __restrict__ ar,
    float* __restrict__ Z, float* __restrict__ el, float* __restrict__ er)
{
    __shared__ float Wl[HD * HD];   // 64 KiB
    __shared__ float xs[2][HD];
    const int tid = threadIdx.x;
    const int col = tid & 127;              // 0..127 = h*32+d
    const int sb  = tid >> 7;               // row sub-group 0/1
    for (int i = tid; i < HD * HD; i += 256) Wl[i] = W[i];
    const int h = col >> 5;
    const float a_l = al[col];
    const float a_r = ar[col];
    __syncthreads();
    const int row0 = blockIdx.x * RPB;
    for (int r = 0; r < RPB; r += 2) {
        const int row = row0 + r + sb;
        if (row < NN) xs[sb][col] = X[row * HD + col];
        __syncthreads();
        if (row < NN) {
            float acc = 0.f;
            #pragma unroll
            for (int k = 0; k < HD; ++k) acc = fmaf(xs[sb][k], Wl[k * HD + col], acc);
            Z[row * HD + col] = acc;
            float pl = acc * a_l, pr = acc * a_r;
            #pragma unroll
            for (int off = 16; off >= 1; off >>= 1) {
                pl += __shfl_xor(pl, off);
                pr += __shfl_xor(pr, off);
            }
            if ((col & 31) == 0) { el[row * NH + h] = pl; er[row * NH + h] = pr; }
        }
        __syncthreads();                    // xs reused next pair
    }
}

// ---------------- CSR build (dst-sorted edge list), once per call ----------------
__global__ void k_deg(const int* __restrict__ dst, int* __restrict__ deg) {
    int t = blockIdx.x * blockDim.x + threadIdx.x;
    if (t < NE) atomicAdd(&deg[dst[t]], 1);
}

// single-block exclusive scan deg[NN] -> offs[NN+1]; also seeds cursor = offs
__global__ __launch_bounds__(1024) void k_scan(const int* __restrict__ deg,
                                               int* __restrict__ offs,
                                               int* __restrict__ cursor)
{
    __shared__ int wsum[16];
    __shared__ int sbase;
    const int tid = threadIdx.x, lane = tid & 63, w = tid >> 6;
    if (tid == 0) sbase = 0;
    __syncthreads();
    for (int start = 0; start < NN; start += 1024) {
        int i = start + tid;
        int v = (i < NN) ? deg[i] : 0;
        int x = v;
        #pragma unroll
        for (int off = 1; off < 64; off <<= 1) {
            int t = __shfl_up(x, off);
            if (lane >= off) x += t;
        }
        if (lane == 63) wsum[w] = x;
        __syncthreads();
        if (w == 0 && lane < 16) {
            int t = wsum[lane];
            #pragma unroll
            for (int off = 1; off < 16; off <<= 1) {
                int u = __shfl_up(t, off);
                if (lane >= off) t += u;
            }
            wsum[lane] = t;   // inclusive scan of wave sums
        }
        __syncthreads();
        int wbase = (w == 0) ? 0 : wsum[w - 1];
        int excl = sbase + wbase + x - v;
        if (i < NN) { offs[i] = excl; cursor[i] = excl; }
        __syncthreads();
        if (tid == 0) sbase += wsum[15];
        __syncthreads();
    }
    if (tid == 0) offs[NN] = sbase;           // == NE
}

__global__ void k_scatter(const int* __restrict__ src, const int* __restrict__ dst,
                          int* __restrict__ cursor, int* __restrict__ csrc) {
    int t = blockIdx.x * blockDim.x + threadIdx.x;
    if (t < NE) {
        int pos = atomicAdd(&cursor[dst[t]], 1);
        csrc[pos] = src[t];
    }
}

// ---- fused edge softmax + aggregate + finalize: one wave per dst node ----
__global__ __launch_bounds__(256) void k_edge_gat(
    const int* __restrict__ offs, const int* __restrict__ csrc,
    const float* __restrict__ el, const float* __restrict__ er,
    const float* __restrict__ Z, const float* __restrict__ b,
    float* __restrict__ X)
{
    int wid = (int)((blockIdx.x * (unsigned)blockDim.x + threadIdx.x) >> 6);
    int lane = threadIdx.x & 63;
    if (wid >= NN) return;
    const int d = wid;
    const int beg = offs[d], end = offs[d + 1];
    const int c0 = lane * 2;
    const int h = lane >> 4;
    const float erd = er[d * NH + h];
    const float2 bb = *(const float2*)&b[c0];

    float m = -INFINITY, sden = 0.f, a0 = 0.f, a1 = 0.f;
    for (int i = beg; i < end; ++i) {
        int s = csrc[i];
        float2 z = *(const float2*)&Z[(size_t)s * HD + c0];
        float e = el[s * NH + h] + erd;
        e = e >= 0.f ? e : NEG_SLOPE * e;
        float nm = fmaxf(m, e);
        float r = __expf(m - nm);      // 0 on first edge (m=-inf)
        float p = __expf(e - nm);
        sden = sden * r + p;
        a0 = a0 * r + z.x * p;
        a1 = a1 * r + z.y * p;
        m = nm;
    }
    float inv = (end > beg) ? 1.f / sden : 0.f;
    float v0 = a0 * inv + bb.x;
    float v1 = a1 * inv + bb.y;
    float2 o;
    o.x = v0 > 0.f ? v0 : 0.f;
    o.y = v1 > 0.f ? v1 : 0.f;
    *(float2*)&X[(size_t)d * HD + c0] = o;
}

// ---- fused mean-pool + classifier: one block per graph (gid is sorted) ----
__global__ __launch_bounds__(128) void k_pool_classify(
    const float* __restrict__ X, const int* __restrict__ gid,
    const float* __restrict__ Wc, const float* __restrict__ bc,
    float* __restrict__ out)
{
    __shared__ float shg[HD];
    __shared__ int slo, shi;
    const int g = blockIdx.x;
    const int c = threadIdx.x;
    if (c == 0) {
        // lower_bound(gid, g) and lower_bound(gid, g+1)
        int lo = 0, hi = NN;
        while (lo < hi) { int mid = (lo + hi) >> 1; if (gid[mid] < g) lo = mid + 1; else hi = mid; }
        slo = lo;
        int lo2 = lo; hi = NN;
        while (lo2 < hi) { int mid = (lo2 + hi) >> 1; if (gid[mid] < g + 1) lo2 = mid + 1; else hi = mid; }
        shi = lo2;
    }
    __syncthreads();
    const int lo = slo, hi = shi;
    float acc = 0.f;
    for (int n = lo; n < hi; ++n) acc += X[(size_t)n * HD + c];
    float cnt = (float)(hi - lo);
    shg[c] = acc / fmaxf(cnt, 1.f);
    __syncthreads();
    if (c < NC) {
        float r = bc[c];
        #pragma unroll
        for (int k = 0; k < HD; ++k) r = fmaf(shg[k], Wc[k * NC + c], r);
        out[g * NC + c] = r;
    }
}

extern "C" void kernel_launch(void* const* d_in, const int* in_sizes, int n_in,
                              void* d_out, int out_size, void* d_ws, size_t ws_size,
                              hipStream_t stream) {
    const float* h    = (const float*)d_in[0];
    const int*   src  = (const int*)  d_in[1];
    const int*   dst  = (const int*)  d_in[2];
    const int*   gid  = (const int*)  d_in[3];
    const float* W1   = (const float*)d_in[4];
    const float* al1  = (const float*)d_in[5];
    const float* ar1  = (const float*)d_in[6];
    const float* b1   = (const float*)d_in[7];
    const float* W2   = (const float*)d_in[8];
    const float* al2  = (const float*)d_in[9];
    const float* ar2  = (const float*)d_in[10];
    const float* b2   = (const float*)d_in[11];
    const float* Wc   = (const float*)d_in[12];
    const float* bc   = (const float*)d_in[13];
    float* out = (float*)d_out;

    char* w = (char*)d_ws;
    float* z    = (float*)w;  w += (size_t)NN * HD * 4;   // 25.6 MB
    float* xb   = (float*)w;  w += (size_t)NN * HD * 4;   // 25.6 MB
    float* el   = (float*)w;  w += (size_t)NN * NH * 4;
    float* er   = (float*)w;  w += (size_t)NN * NH * 4;
    int*   deg  = (int*)w;    w += (size_t)NN * 4;
    int*   offs = (int*)w;    w += (size_t)(NN + 1) * 4;
    int*   curs = (int*)w;    w += (size_t)NN * 4;
    int*   csrc = (int*)w;    w += (size_t)NE * 4;        // 3.2 MB

    const int TB = 256;
    const int gE    = (NE + TB - 1) / TB;
    const int gGemm = (NN + RPB - 1) / RPB;
    const int gEdge = (NN * 64 + TB - 1) / TB;   // one wave per dst

    // ---------------- CSR build (dst constant across layers) ----------------
    hipMemsetAsync(deg, 0, (size_t)NN * 4, stream);
    k_deg<<<gE, TB, 0, stream>>>(dst, deg);
    k_scan<<<1, 1024, 0, stream>>>(deg, offs, curs);
    k_scatter<<<gE, TB, 0, stream>>>(src, dst, curs, csrc);

    // ---------------- layer 1 ----------------
    k_gemm_attn<<<gGemm, 256, 0, stream>>>(h, W1, al1, ar1, z, el, er);
    k_edge_gat<<<gEdge, TB, 0, stream>>>(offs, csrc, el, er, z, b1, xb);

    // ---------------- layer 2 ----------------
    k_gemm_attn<<<gGemm, 256, 0, stream>>>(xb, W2, al2, ar2, z, el, er);
    k_edge_gat<<<gEdge, TB, 0, stream>>>(offs, csrc, el, er, z, b2, xb);

    // ---------------- fused pooling + classifier ----------------
    k_pool_classify<<<NG, 128, 0, stream>>>(xb, gid, Wc, bc, out);
}

// Round 4
// 576.893 us; speedup vs baseline: 3.0134x; 1.3083x over previous
//
#include <hip/hip_runtime.h>
#include <math.h>

#define NN 50000      // nodes
#define NE 800000     // edges
#define NG 128        // graphs
#define HD 128        // H*D
#define NH 4          // heads
#define NC 10         // classes
#define NEG_SLOPE 0.2f

// ---- register-tiled GEMM (x[N,128] @ W[128,128]) fused with el/er logits ----
// 256 threads = 16 ty (rows) x 16 tx (cols). TM=8 rows, TN=8 cols
// (cols 4tx..4tx+3 and 64+4tx..64+4tx+3). W staged in LDS [k][col] natural;
// X read directly from global with 16-lane broadcast (no staging, no redundancy).
#define BM 128
__global__ __launch_bounds__(256, 2) void k_gemm_attn(
    const float* __restrict__ X, const float* __restrict__ W,
    const float* __restrict__ al, const float* __restrict__ ar,
    float* __restrict__ Z, float* __restrict__ el, float* __restrict__ er)
{
    __shared__ float Ws[HD * HD];   // 64 KiB, [k][col]
    const int tid = threadIdx.x;
    // stage W as float4s, coalesced
    {
        const float4* Wg = (const float4*)W;
        float4* Wl = (float4*)Ws;
        #pragma unroll
        for (int i = 0; i < 16; ++i) Wl[i * 256 + tid] = Wg[i * 256 + tid];
    }
    const int tx = tid & 15, ty = tid >> 4;
    const int cA = 4 * tx;          // head hA = tx>>3 (0/1)
    const int cB = 64 + 4 * tx;     // head hA+2
    const int row0 = blockIdx.x * BM + ty * 8;

    int rows[8];
    #pragma unroll
    for (int i = 0; i < 8; ++i) {
        int r = row0 + i;
        rows[i] = r < NN ? r : NN - 1;   // clamp; stores guarded later
    }

    float acc[8][8];
    #pragma unroll
    for (int i = 0; i < 8; ++i)
        #pragma unroll
        for (int j = 0; j < 8; ++j) acc[i][j] = 0.f;

    __syncthreads();

    #pragma unroll 2
    for (int k0 = 0; k0 < HD; k0 += 4) {
        float4 xv[8];
        #pragma unroll
        for (int i = 0; i < 8; ++i)
            xv[i] = *(const float4*)&X[(size_t)rows[i] * HD + k0];
        float4 wa[4], wb[4];
        #pragma unroll
        for (int kk = 0; kk < 4; ++kk) {
            wa[kk] = *(const float4*)&Ws[(k0 + kk) * HD + cA];
            wb[kk] = *(const float4*)&Ws[(k0 + kk) * HD + cB];
        }
        #pragma unroll
        for (int i = 0; i < 8; ++i) {
            float x0 = xv[i].x, x1 = xv[i].y, x2 = xv[i].z, x3 = xv[i].w;
            acc[i][0] = fmaf(x0, wa[0].x, acc[i][0]);
            acc[i][1] = fmaf(x0, wa[0].y, acc[i][1]);
            acc[i][2] = fmaf(x0, wa[0].z, acc[i][2]);
            acc[i][3] = fmaf(x0, wa[0].w, acc[i][3]);
            acc[i][4] = fmaf(x0, wb[0].x, acc[i][4]);
            acc[i][5] = fmaf(x0, wb[0].y, acc[i][5]);
            acc[i][6] = fmaf(x0, wb[0].z, acc[i][6]);
            acc[i][7] = fmaf(x0, wb[0].w, acc[i][7]);
            acc[i][0] = fmaf(x1, wa[1].x, acc[i][0]);
            acc[i][1] = fmaf(x1, wa[1].y, acc[i][1]);
            acc[i][2] = fmaf(x1, wa[1].z, acc[i][2]);
            acc[i][3] = fmaf(x1, wa[1].w, acc[i][3]);
            acc[i][4] = fmaf(x1, wb[1].x, acc[i][4]);
            acc[i][5] = fmaf(x1, wb[1].y, acc[i][5]);
            acc[i][6] = fmaf(x1, wb[1].z, acc[i][6]);
            acc[i][7] = fmaf(x1, wb[1].w, acc[i][7]);
            acc[i][0] = fmaf(x2, wa[2].x, acc[i][0]);
            acc[i][1] = fmaf(x2, wa[2].y, acc[i][1]);
            acc[i][2] = fmaf(x2, wa[2].z, acc[i][2]);
            acc[i][3] = fmaf(x2, wa[2].w, acc[i][3]);
            acc[i][4] = fmaf(x2, wb[2].x, acc[i][4]);
            acc[i][5] = fmaf(x2, wb[2].y, acc[i][5]);
            acc[i][6] = fmaf(x2, wb[2].z, acc[i][6]);
            acc[i][7] = fmaf(x2, wb[2].w, acc[i][7]);
            acc[i][0] = fmaf(x3, wa[3].x, acc[i][0]);
            acc[i][1] = fmaf(x3, wa[3].y, acc[i][1]);
            acc[i][2] = fmaf(x3, wa[3].z, acc[i][2]);
            acc[i][3] = fmaf(x3, wa[3].w, acc[i][3]);
            acc[i][4] = fmaf(x3, wb[3].x, acc[i][4]);
            acc[i][5] = fmaf(x3, wb[3].y, acc[i][5]);
            acc[i][6] = fmaf(x3, wb[3].z, acc[i][6]);
            acc[i][7] = fmaf(x3, wb[3].w, acc[i][7]);
        }
    }

    // attention logit partials + reduce over tx bits 0..2 (8 col-threads/head)
    const float4 alA = *(const float4*)&al[cA];
    const float4 alB = *(const float4*)&al[cB];
    const float4 arA = *(const float4*)&ar[cA];
    const float4 arB = *(const float4*)&ar[cB];
    const int hA = tx >> 3;

    #pragma unroll
    for (int i = 0; i < 8; ++i) {
        int r = row0 + i;
        float plA = acc[i][0] * alA.x + acc[i][1] * alA.y + acc[i][2] * alA.z + acc[i][3] * alA.w;
        float prA = acc[i][0] * arA.x + acc[i][1] * arA.y + acc[i][2] * arA.z + acc[i][3] * arA.w;
        float plB = acc[i][4] * alB.x + acc[i][5] * alB.y + acc[i][6] * alB.z + acc[i][7] * alB.w;
        float prB = acc[i][4] * arB.x + acc[i][5] * arB.y + acc[i][6] * arB.z + acc[i][7] * arB.w;
        #pragma unroll
        for (int off = 1; off <= 4; off <<= 1) {
            plA += __shfl_xor(plA, off);
            prA += __shfl_xor(prA, off);
            plB += __shfl_xor(plB, off);
            prB += __shfl_xor(prB, off);
        }
        if ((tx & 7) == 0 && r < NN) {
            el[r * NH + hA]     = plA;
            er[r * NH + hA]     = prA;
            el[r * NH + hA + 2] = plB;
            er[r * NH + hA + 2] = prB;
        }
        if (r < NN) {
            *(float4*)&Z[(size_t)r * HD + cA] = make_float4(acc[i][0], acc[i][1], acc[i][2], acc[i][3]);
            *(float4*)&Z[(size_t)r * HD + cB] = make_float4(acc[i][4], acc[i][5], acc[i][6], acc[i][7]);
        }
    }
}

// ---------------- CSR build (dst-sorted edge list), once per call ----------------
__global__ void k_deg(const int* __restrict__ dst, int* __restrict__ deg) {
    int t = blockIdx.x * blockDim.x + threadIdx.x;
    if (t < NE) atomicAdd(&deg[dst[t]], 1);
}

// single-block exclusive scan deg[NN] -> offs[NN+1]; also seeds cursor = offs
__global__ __launch_bounds__(1024) void k_scan(const int* __restrict__ deg,
                                               int* __restrict__ offs,
                                               int* __restrict__ cursor)
{
    __shared__ int wsum[16];
    __shared__ int sbase;
    const int tid = threadIdx.x, lane = tid & 63, w = tid >> 6;
    if (tid == 0) sbase = 0;
    __syncthreads();
    for (int start = 0; start < NN; start += 1024) {
        int i = start + tid;
        int v = (i < NN) ? deg[i] : 0;
        int x = v;
        #pragma unroll
        for (int off = 1; off < 64; off <<= 1) {
            int t = __shfl_up(x, off);
            if (lane >= off) x += t;
        }
        if (lane == 63) wsum[w] = x;
        __syncthreads();
        if (w == 0 && lane < 16) {
            int t = wsum[lane];
            #pragma unroll
            for (int off = 1; off < 16; off <<= 1) {
                int u = __shfl_up(t, off);
                if (lane >= off) t += u;
            }
            wsum[lane] = t;
        }
        __syncthreads();
        int wbase = (w == 0) ? 0 : wsum[w - 1];
        int excl = sbase + wbase + x - v;
        if (i < NN) { offs[i] = excl; cursor[i] = excl; }
        __syncthreads();
        if (tid == 0) sbase += wsum[15];
        __syncthreads();
    }
    if (tid == 0) offs[NN] = sbase;           // == NE
}

__global__ void k_scatter(const int* __restrict__ src, const int* __restrict__ dst,
                          int* __restrict__ cursor, int* __restrict__ csrc) {
    int t = blockIdx.x * blockDim.x + threadIdx.x;
    if (t < NE) {
        int pos = atomicAdd(&cursor[dst[t]], 1);
        csrc[pos] = src[t];
    }
}

// ---- fused edge softmax + aggregate + finalize: one wave per dst node ----
__global__ __launch_bounds__(256) void k_edge_gat(
    const int* __restrict__ offs, const int* __restrict__ csrc,
    const float* __restrict__ el, const float* __restrict__ er,
    const float* __restrict__ Z, const float* __restrict__ b,
    float* __restrict__ X)
{
    int wid = (int)((blockIdx.x * (unsigned)blockDim.x + threadIdx.x) >> 6);
    int lane = threadIdx.x & 63;
    if (wid >= NN) return;
    const int d = wid;
    const int beg = offs[d], end = offs[d + 1];
    const int c0 = lane * 2;
    const int h = lane >> 4;
    const float erd = er[d * NH + h];
    const float2 bb = *(const float2*)&b[c0];

    float m = -INFINITY, sden = 0.f, a0 = 0.f, a1 = 0.f;
    for (int i = beg; i < end; ++i) {
        int s = csrc[i];
        float2 z = *(const float2*)&Z[(size_t)s * HD + c0];
        float e = el[s * NH + h] + erd;
        e = e >= 0.f ? e : NEG_SLOPE * e;
        float nm = fmaxf(m, e);
        float r = __expf(m - nm);      // 0 on first edge (m=-inf)
        float p = __expf(e - nm);
        sden = sden * r + p;
        a0 = a0 * r + z.x * p;
        a1 = a1 * r + z.y * p;
        m = nm;
    }
    float inv = (end > beg) ? 1.f / sden : 0.f;
    float v0 = a0 * inv + bb.x;
    float v1 = a1 * inv + bb.y;
    float2 o;
    o.x = v0 > 0.f ? v0 : 0.f;
    o.y = v1 > 0.f ? v1 : 0.f;
    *(float2*)&X[(size_t)d * HD + c0] = o;
}

// ---- fused mean-pool + classifier: one block per graph (gid is sorted) ----
__global__ __launch_bounds__(128) void k_pool_classify(
    const float* __restrict__ X, const int* __restrict__ gid,
    const float* __restrict__ Wc, const float* __restrict__ bc,
    float* __restrict__ out)
{
    __shared__ float shg[HD];
    __shared__ int slo, shi;
    const int g = blockIdx.x;
    const int c = threadIdx.x;
    if (c == 0) {
        int lo = 0, hi = NN;
        while (lo < hi) { int mid = (lo + hi) >> 1; if (gid[mid] < g) lo = mid + 1; else hi = mid; }
        slo = lo;
        int lo2 = lo; hi = NN;
        while (lo2 < hi) { int mid = (lo2 + hi) >> 1; if (gid[mid] < g + 1) lo2 = mid + 1; else hi = mid; }
        shi = lo2;
    }
    __syncthreads();
    const int lo = slo, hi = shi;
    float acc = 0.f;
    for (int n = lo; n < hi; ++n) acc += X[(size_t)n * HD + c];
    float cnt = (float)(hi - lo);
    shg[c] = acc / fmaxf(cnt, 1.f);
    __syncthreads();
    if (c < NC) {
        float r = bc[c];
        #pragma unroll
        for (int k = 0; k < HD; ++k) r = fmaf(shg[k], Wc[k * NC + c], r);
        out[g * NC + c] = r;
    }
}

extern "C" void kernel_launch(void* const* d_in, const int* in_sizes, int n_in,
                              void* d_out, int out_size, void* d_ws, size_t ws_size,
                              hipStream_t stream) {
    const float* h    = (const float*)d_in[0];
    const int*   src  = (const int*)  d_in[1];
    const int*   dst  = (const int*)  d_in[2];
    const int*   gid  = (const int*)  d_in[3];
    const float* W1   = (const float*)d_in[4];
    const float* al1  = (const float*)d_in[5];
    const float* ar1  = (const float*)d_in[6];
    const float* b1   = (const float*)d_in[7];
    const float* W2   = (const float*)d_in[8];
    const float* al2  = (const float*)d_in[9];
    const float* ar2  = (const float*)d_in[10];
    const float* b2   = (const float*)d_in[11];
    const float* Wc   = (const float*)d_in[12];
    const float* bc   = (const float*)d_in[13];
    float* out = (float*)d_out;

    char* w = (char*)d_ws;
    float* z    = (float*)w;  w += (size_t)NN * HD * 4;   // 25.6 MB
    float* xb   = (float*)w;  w += (size_t)NN * HD * 4;   // 25.6 MB
    float* el   = (float*)w;  w += (size_t)NN * NH * 4;
    float* er   = (float*)w;  w += (size_t)NN * NH * 4;
    int*   deg  = (int*)w;    w += (size_t)NN * 4;
    int*   offs = (int*)w;    w += (size_t)(NN + 1) * 4;
    int*   curs = (int*)w;    w += (size_t)NN * 4;
    int*   csrc = (int*)w;    w += (size_t)NE * 4;        // 3.2 MB

    const int TB = 256;
    const int gE    = (NE + TB - 1) / TB;
    const int gGemm = (NN + BM - 1) / BM;        // 391
    const int gEdge = (NN * 64 + TB - 1) / TB;   // one wave per dst

    // ---------------- CSR build (dst constant across layers) ----------------
    hipMemsetAsync(deg, 0, (size_t)NN * 4, stream);
    k_deg<<<gE, TB, 0, stream>>>(dst, deg);
    k_scan<<<1, 1024, 0, stream>>>(deg, offs, curs);
    k_scatter<<<gE, TB, 0, stream>>>(src, dst, curs, csrc);

    // ---------------- layer 1 ----------------
    k_gemm_attn<<<gGemm, 256, 0, stream>>>(h, W1, al1, ar1, z, el, er);
    k_edge_gat<<<gEdge, TB, 0, stream>>>(offs, csrc, el, er, z, b1, xb);

    // ---------------- layer 2 ----------------
    k_gemm_attn<<<gGemm, 256, 0, stream>>>(xb, W2, al2, ar2, z, el, er);
    k_edge_gat<<<gEdge, TB, 0, stream>>>(offs, csrc, el, er, z, b2, xb);

    // ---------------- fused pooling + classifier ----------------
    k_pool_classify<<<NG, 128, 0, stream>>>(xb, gid, Wc, bc, out);
}

// Round 5
// 413.359 us; speedup vs baseline: 4.2056x; 1.3956x over previous
//
#include <hip/hip_runtime.h>
#include <hip/hip_fp16.h>
#include <math.h>

#define NN 50000      // nodes
#define NE 800000     // edges
#define NG 128        // graphs
#define HD 128        // H*D
#define NH 4          // heads
#define NC 10         // classes
#define NEG_SLOPE 0.2f

// ---- register-tiled GEMM (x[N,128] @ W[128,128]) fused with el/er logits ----
// 256 threads = 16 ty (rows) x 16 tx (cols). TM=8 rows, TN=8 cols.
// W staged in LDS [k][col]; X read directly from global (16-lane broadcast).
// Z stored as fp16 (fp32 accumulate, convert at store) for the edge gather.
#define BM 128
__global__ __launch_bounds__(256, 2) void k_gemm_attn(
    const float* __restrict__ X, const float* __restrict__ W,
    const float* __restrict__ al, const float* __restrict__ ar,
    __half* __restrict__ Zh, float* __restrict__ el, float* __restrict__ er)
{
    __shared__ float Ws[HD * HD];   // 64 KiB, [k][col]
    const int tid = threadIdx.x;
    {
        const float4* Wg = (const float4*)W;
        float4* Wl = (float4*)Ws;
        #pragma unroll
        for (int i = 0; i < 16; ++i) Wl[i * 256 + tid] = Wg[i * 256 + tid];
    }
    const int tx = tid & 15, ty = tid >> 4;
    const int cA = 4 * tx;          // head hA = tx>>3 (0/1)
    const int cB = 64 + 4 * tx;     // head hA+2
    const int row0 = blockIdx.x * BM + ty * 8;

    int rows[8];
    #pragma unroll
    for (int i = 0; i < 8; ++i) {
        int r = row0 + i;
        rows[i] = r < NN ? r : NN - 1;   // clamp; stores guarded later
    }

    float acc[8][8];
    #pragma unroll
    for (int i = 0; i < 8; ++i)
        #pragma unroll
        for (int j = 0; j < 8; ++j) acc[i][j] = 0.f;

    __syncthreads();

    #pragma unroll 2
    for (int k0 = 0; k0 < HD; k0 += 4) {
        float4 xv[8];
        #pragma unroll
        for (int i = 0; i < 8; ++i)
            xv[i] = *(const float4*)&X[(size_t)rows[i] * HD + k0];
        float4 wa[4], wb[4];
        #pragma unroll
        for (int kk = 0; kk < 4; ++kk) {
            wa[kk] = *(const float4*)&Ws[(k0 + kk) * HD + cA];
            wb[kk] = *(const float4*)&Ws[(k0 + kk) * HD + cB];
        }
        #pragma unroll
        for (int i = 0; i < 8; ++i) {
            float x0 = xv[i].x, x1 = xv[i].y, x2 = xv[i].z, x3 = xv[i].w;
            acc[i][0] = fmaf(x0, wa[0].x, acc[i][0]);
            acc[i][1] = fmaf(x0, wa[0].y, acc[i][1]);
            acc[i][2] = fmaf(x0, wa[0].z, acc[i][2]);
            acc[i][3] = fmaf(x0, wa[0].w, acc[i][3]);
            acc[i][4] = fmaf(x0, wb[0].x, acc[i][4]);
            acc[i][5] = fmaf(x0, wb[0].y, acc[i][5]);
            acc[i][6] = fmaf(x0, wb[0].z, acc[i][6]);
            acc[i][7] = fmaf(x0, wb[0].w, acc[i][7]);
            acc[i][0] = fmaf(x1, wa[1].x, acc[i][0]);
            acc[i][1] = fmaf(x1, wa[1].y, acc[i][1]);
            acc[i][2] = fmaf(x1, wa[1].z, acc[i][2]);
            acc[i][3] = fmaf(x1, wa[1].w, acc[i][3]);
            acc[i][4] = fmaf(x1, wb[1].x, acc[i][4]);
            acc[i][5] = fmaf(x1, wb[1].y, acc[i][5]);
            acc[i][6] = fmaf(x1, wb[1].z, acc[i][6]);
            acc[i][7] = fmaf(x1, wb[1].w, acc[i][7]);
            acc[i][0] = fmaf(x2, wa[2].x, acc[i][0]);
            acc[i][1] = fmaf(x2, wa[2].y, acc[i][1]);
            acc[i][2] = fmaf(x2, wa[2].z, acc[i][2]);
            acc[i][3] = fmaf(x2, wa[2].w, acc[i][3]);
            acc[i][4] = fmaf(x2, wb[2].x, acc[i][4]);
            acc[i][5] = fmaf(x2, wb[2].y, acc[i][5]);
            acc[i][6] = fmaf(x2, wb[2].z, acc[i][6]);
            acc[i][7] = fmaf(x2, wb[2].w, acc[i][7]);
            acc[i][0] = fmaf(x3, wa[3].x, acc[i][0]);
            acc[i][1] = fmaf(x3, wa[3].y, acc[i][1]);
            acc[i][2] = fmaf(x3, wa[3].z, acc[i][2]);
            acc[i][3] = fmaf(x3, wa[3].w, acc[i][3]);
            acc[i][4] = fmaf(x3, wb[3].x, acc[i][4]);
            acc[i][5] = fmaf(x3, wb[3].y, acc[i][5]);
            acc[i][6] = fmaf(x3, wb[3].z, acc[i][6]);
            acc[i][7] = fmaf(x3, wb[3].w, acc[i][7]);
        }
    }

    const float4 alA = *(const float4*)&al[cA];
    const float4 alB = *(const float4*)&al[cB];
    const float4 arA = *(const float4*)&ar[cA];
    const float4 arB = *(const float4*)&ar[cB];
    const int hA = tx >> 3;

    #pragma unroll
    for (int i = 0; i < 8; ++i) {
        int r = row0 + i;
        float plA = acc[i][0] * alA.x + acc[i][1] * alA.y + acc[i][2] * alA.z + acc[i][3] * alA.w;
        float prA = acc[i][0] * arA.x + acc[i][1] * arA.y + acc[i][2] * arA.z + acc[i][3] * arA.w;
        float plB = acc[i][4] * alB.x + acc[i][5] * alB.y + acc[i][6] * alB.z + acc[i][7] * alB.w;
        float prB = acc[i][4] * arB.x + acc[i][5] * arB.y + acc[i][6] * arB.z + acc[i][7] * arB.w;
        #pragma unroll
        for (int off = 1; off <= 4; off <<= 1) {
            plA += __shfl_xor(plA, off);
            prA += __shfl_xor(prA, off);
            plB += __shfl_xor(plB, off);
            prB += __shfl_xor(prB, off);
        }
        if ((tx & 7) == 0 && r < NN) {
            el[r * NH + hA]     = plA;
            er[r * NH + hA]     = prA;
            el[r * NH + hA + 2] = plB;
            er[r * NH + hA + 2] = prB;
        }
        if (r < NN) {
            __half2 pA0 = __floats2half2_rn(acc[i][0], acc[i][1]);
            __half2 pA1 = __floats2half2_rn(acc[i][2], acc[i][3]);
            __half2 pB0 = __floats2half2_rn(acc[i][4], acc[i][5]);
            __half2 pB1 = __floats2half2_rn(acc[i][6], acc[i][7]);
            uint2 ua, ub;
            ua.x = *(unsigned*)&pA0; ua.y = *(unsigned*)&pA1;
            ub.x = *(unsigned*)&pB0; ub.y = *(unsigned*)&pB1;
            *(uint2*)&Zh[(size_t)r * HD + cA] = ua;
            *(uint2*)&Zh[(size_t)r * HD + cB] = ub;
        }
    }
}

// ---------------- CSR build (dst-sorted edge list), once per call ----------------
__global__ void k_deg(const int* __restrict__ dst, int* __restrict__ deg) {
    int t = blockIdx.x * blockDim.x + threadIdx.x;
    if (t < NE) atomicAdd(&deg[dst[t]], 1);
}

__global__ __launch_bounds__(1024) void k_scan(const int* __restrict__ deg,
                                               int* __restrict__ offs,
                                               int* __restrict__ cursor)
{
    __shared__ int wsum[16];
    __shared__ int sbase;
    const int tid = threadIdx.x, lane = tid & 63, w = tid >> 6;
    if (tid == 0) sbase = 0;
    __syncthreads();
    for (int start = 0; start < NN; start += 1024) {
        int i = start + tid;
        int v = (i < NN) ? deg[i] : 0;
        int x = v;
        #pragma unroll
        for (int off = 1; off < 64; off <<= 1) {
            int t = __shfl_up(x, off);
            if (lane >= off) x += t;
        }
        if (lane == 63) wsum[w] = x;
        __syncthreads();
        if (w == 0 && lane < 16) {
            int t = wsum[lane];
            #pragma unroll
            for (int off = 1; off < 16; off <<= 1) {
                int u = __shfl_up(t, off);
                if (lane >= off) t += u;
            }
            wsum[lane] = t;
        }
        __syncthreads();
        int wbase = (w == 0) ? 0 : wsum[w - 1];
        int excl = sbase + wbase + x - v;
        if (i < NN) { offs[i] = excl; cursor[i] = excl; }
        __syncthreads();
        if (tid == 0) sbase += wsum[15];
        __syncthreads();
    }
    if (tid == 0) offs[NN] = sbase;           // == NE
}

__global__ void k_scatter(const int* __restrict__ src, const int* __restrict__ dst,
                          int* __restrict__ cursor, int* __restrict__ csrc) {
    int t = blockIdx.x * blockDim.x + threadIdx.x;
    if (t < NE) {
        int pos = atomicAdd(&cursor[dst[t]], 1);
        csrc[pos] = src[t];
    }
}

// ---- fused edge softmax + aggregate + finalize: one wave per dst node ----
// lane owns channels c0=2*lane, c0+1 (head h=lane>>4); z gathered as fp16.
__global__ __launch_bounds__(256) void k_edge_gat(
    const int* __restrict__ offs, const int* __restrict__ csrc,
    const float* __restrict__ el, const float* __restrict__ er,
    const __half* __restrict__ Zh, const float* __restrict__ b,
    float* __restrict__ X)
{
    int wid = (int)((blockIdx.x * (unsigned)blockDim.x + threadIdx.x) >> 6);
    int lane = threadIdx.x & 63;
    if (wid >= NN) return;
    const int d = wid;
    const int beg = offs[d], end = offs[d + 1];
    const int c0 = lane * 2;
    const int h = lane >> 4;
    const float erd = er[d * NH + h];
    const float2 bb = *(const float2*)&b[c0];

    float m = -INFINITY, sden = 0.f, a0 = 0.f, a1 = 0.f;
    int i = beg;
    for (; i + 1 < end; i += 2) {
        int s1 = csrc[i], s2 = csrc[i + 1];
        __half2 zh1 = *(const __half2*)&Zh[(size_t)s1 * HD + c0];
        __half2 zh2 = *(const __half2*)&Zh[(size_t)s2 * HD + c0];
        float e1 = el[s1 * NH + h] + erd;
        float e2 = el[s2 * NH + h] + erd;
        e1 = e1 >= 0.f ? e1 : NEG_SLOPE * e1;
        e2 = e2 >= 0.f ? e2 : NEG_SLOPE * e2;
        float2 z1 = __half22float2(zh1);
        float2 z2 = __half22float2(zh2);
        float nm = fmaxf(m, fmaxf(e1, e2));
        float r  = __expf(m - nm);     // 0 when m was -inf
        float p1 = __expf(e1 - nm);
        float p2 = __expf(e2 - nm);
        sden = sden * r + p1 + p2;
        a0 = a0 * r + z1.x * p1 + z2.x * p2;
        a1 = a1 * r + z1.y * p1 + z2.y * p2;
        m = nm;
    }
    if (i < end) {
        int s = csrc[i];
        __half2 zh = *(const __half2*)&Zh[(size_t)s * HD + c0];
        float e = el[s * NH + h] + erd;
        e = e >= 0.f ? e : NEG_SLOPE * e;
        float2 z = __half22float2(zh);
        float nm = fmaxf(m, e);
        float r = __expf(m - nm);
        float p = __expf(e - nm);
        sden = sden * r + p;
        a0 = a0 * r + z.x * p;
        a1 = a1 * r + z.y * p;
    }
    float inv = (end > beg) ? 1.f / sden : 0.f;
    float v0 = a0 * inv + bb.x;
    float v1 = a1 * inv + bb.y;
    float2 o;
    o.x = v0 > 0.f ? v0 : 0.f;
    o.y = v1 > 0.f ? v1 : 0.f;
    *(float2*)&X[(size_t)d * HD + c0] = o;
}

// ---- fused mean-pool + classifier: one 1024-thread block per graph ----
__global__ __launch_bounds__(1024) void k_pool_classify(
    const float* __restrict__ X, const int* __restrict__ gid,
    const float* __restrict__ Wc, const float* __restrict__ bc,
    float* __restrict__ out)
{
    __shared__ float part[8][HD];
    __shared__ float shg[HD];
    __shared__ int slo, shi;
    const int g = blockIdx.x;
    const int tid = threadIdx.x;
    const int c = tid & 127;
    const int gr = tid >> 7;            // 8 row-groups
    if (tid == 0) {
        int lo = 0, hi = NN;
        while (lo < hi) { int mid = (lo + hi) >> 1; if (gid[mid] < g) lo = mid + 1; else hi = mid; }
        slo = lo;
        int lo2 = lo; hi = NN;
        while (lo2 < hi) { int mid = (lo2 + hi) >> 1; if (gid[mid] < g + 1) lo2 = mid + 1; else hi = mid; }
        shi = lo2;
    }
    __syncthreads();
    const int lo = slo, hi = shi;
    float acc = 0.f;
    for (int n = lo + gr; n < hi; n += 8) acc += X[(size_t)n * HD + c];
    part[gr][c] = acc;
    __syncthreads();
    if (gr == 0) {
        float s = part[0][c] + part[1][c] + part[2][c] + part[3][c]
                + part[4][c] + part[5][c] + part[6][c] + part[7][c];
        shg[c] = s / fmaxf((float)(hi - lo), 1.f);
    }
    __syncthreads();
    if (tid < NC) {
        float r = bc[tid];
        #pragma unroll
        for (int k = 0; k < HD; ++k) r = fmaf(shg[k], Wc[k * NC + tid], r);
        out[g * NC + tid] = r;
    }
}

extern "C" void kernel_launch(void* const* d_in, const int* in_sizes, int n_in,
                              void* d_out, int out_size, void* d_ws, size_t ws_size,
                              hipStream_t stream) {
    const float* h    = (const float*)d_in[0];
    const int*   src  = (const int*)  d_in[1];
    const int*   dst  = (const int*)  d_in[2];
    const int*   gid  = (const int*)  d_in[3];
    const float* W1   = (const float*)d_in[4];
    const float* al1  = (const float*)d_in[5];
    const float* ar1  = (const float*)d_in[6];
    const float* b1   = (const float*)d_in[7];
    const float* W2   = (const float*)d_in[8];
    const float* al2  = (const float*)d_in[9];
    const float* ar2  = (const float*)d_in[10];
    const float* b2   = (const float*)d_in[11];
    const float* Wc   = (const float*)d_in[12];
    const float* bc   = (const float*)d_in[13];
    float* out = (float*)d_out;

    char* w = (char*)d_ws;
    __half* zh  = (__half*)w; w += (size_t)NN * HD * 2;   // 12.8 MB
    float* xb   = (float*)w;  w += (size_t)NN * HD * 4;   // 25.6 MB
    float* el   = (float*)w;  w += (size_t)NN * NH * 4;
    float* er   = (float*)w;  w += (size_t)NN * NH * 4;
    int*   deg  = (int*)w;    w += (size_t)NN * 4;
    int*   offs = (int*)w;    w += (size_t)(NN + 1) * 4;
    int*   curs = (int*)w;    w += (size_t)NN * 4;
    int*   csrc = (int*)w;    w += (size_t)NE * 4;        // 3.2 MB

    const int TB = 256;
    const int gE    = (NE + TB - 1) / TB;
    const int gGemm = (NN + BM - 1) / BM;        // 391
    const int gEdge = (NN * 64 + TB - 1) / TB;   // one wave per dst

    // ---------------- CSR build (dst constant across layers) ----------------
    hipMemsetAsync(deg, 0, (size_t)NN * 4, stream);
    k_deg<<<gE, TB, 0, stream>>>(dst, deg);
    k_scan<<<1, 1024, 0, stream>>>(deg, offs, curs);
    k_scatter<<<gE, TB, 0, stream>>>(src, dst, curs, csrc);

    // ---------------- layer 1 ----------------
    k_gemm_attn<<<gGemm, 256, 0, stream>>>(h, W1, al1, ar1, zh, el, er);
    k_edge_gat<<<gEdge, TB, 0, stream>>>(offs, csrc, el, er, zh, b1, xb);

    // ---------------- layer 2 ----------------
    k_gemm_attn<<<gGemm, 256, 0, stream>>>(xb, W2, al2, ar2, zh, el, er);
    k_edge_gat<<<gEdge, TB, 0, stream>>>(offs, csrc, el, er, zh, b2, xb);

    // ---------------- fused pooling + classifier ----------------
    k_pool_classify<<<NG, 1024, 0, stream>>>(xb, gid, Wc, bc, out);
}

// Round 8
// 352.970 us; speedup vs baseline: 4.9251x; 1.1711x over previous
//
#include <hip/hip_runtime.h>
#include <hip/hip_fp16.h>
#include <math.h>

#define NN 50000      // nodes
#define NE 800000     // edges
#define NG 128        // graphs
#define HD 128        // H*D
#define NH 4          // heads
#define NC 10         // classes
#define NEG_SLOPE 0.2f

// ---- register-tiled GEMM (x[N,128] @ W[128,128]) fused with el/er logits ----
#define BM 128
__global__ __launch_bounds__(256, 2) void k_gemm_attn(
    const float* __restrict__ X, const float* __restrict__ W,
    const float* __restrict__ al, const float* __restrict__ ar,
    __half* __restrict__ Zh, float* __restrict__ el, float* __restrict__ er)
{
    __shared__ float Ws[HD * HD];   // 64 KiB, [k][col]
    const int tid = threadIdx.x;
    {
        const float4* Wg = (const float4*)W;
        float4* Wl = (float4*)Ws;
        #pragma unroll
        for (int i = 0; i < 16; ++i) Wl[i * 256 + tid] = Wg[i * 256 + tid];
    }
    const int tx = tid & 15, ty = tid >> 4;
    const int cA = 4 * tx;          // head hA = tx>>3 (0/1)
    const int cB = 64 + 4 * tx;     // head hA+2
    const int row0 = blockIdx.x * BM + ty * 8;

    int rows[8];
    #pragma unroll
    for (int i = 0; i < 8; ++i) {
        int r = row0 + i;
        rows[i] = r < NN ? r : NN - 1;   // clamp; stores guarded later
    }

    float acc[8][8];
    #pragma unroll
    for (int i = 0; i < 8; ++i)
        #pragma unroll
        for (int j = 0; j < 8; ++j) acc[i][j] = 0.f;

    __syncthreads();

    #pragma unroll 2
    for (int k0 = 0; k0 < HD; k0 += 4) {
        float4 xv[8];
        #pragma unroll
        for (int i = 0; i < 8; ++i)
            xv[i] = *(const float4*)&X[(size_t)rows[i] * HD + k0];
        float4 wa[4], wb[4];
        #pragma unroll
        for (int kk = 0; kk < 4; ++kk) {
            wa[kk] = *(const float4*)&Ws[(k0 + kk) * HD + cA];
            wb[kk] = *(const float4*)&Ws[(k0 + kk) * HD + cB];
        }
        #pragma unroll
        for (int i = 0; i < 8; ++i) {
            float x0 = xv[i].x, x1 = xv[i].y, x2 = xv[i].z, x3 = xv[i].w;
            acc[i][0] = fmaf(x0, wa[0].x, acc[i][0]);
            acc[i][1] = fmaf(x0, wa[0].y, acc[i][1]);
            acc[i][2] = fmaf(x0, wa[0].z, acc[i][2]);
            acc[i][3] = fmaf(x0, wa[0].w, acc[i][3]);
            acc[i][4] = fmaf(x0, wb[0].x, acc[i][4]);
            acc[i][5] = fmaf(x0, wb[0].y, acc[i][5]);
            acc[i][6] = fmaf(x0, wb[0].z, acc[i][6]);
            acc[i][7] = fmaf(x0, wb[0].w, acc[i][7]);
            acc[i][0] = fmaf(x1, wa[1].x, acc[i][0]);
            acc[i][1] = fmaf(x1, wa[1].y, acc[i][1]);
            acc[i][2] = fmaf(x1, wa[1].z, acc[i][2]);
            acc[i][3] = fmaf(x1, wa[1].w, acc[i][3]);
            acc[i][4] = fmaf(x1, wb[1].x, acc[i][4]);
            acc[i][5] = fmaf(x1, wb[1].y, acc[i][5]);
            acc[i][6] = fmaf(x1, wb[1].z, acc[i][6]);
            acc[i][7] = fmaf(x1, wb[1].w, acc[i][7]);
            acc[i][0] = fmaf(x2, wa[2].x, acc[i][0]);
            acc[i][1] = fmaf(x2, wa[2].y, acc[i][1]);
            acc[i][2] = fmaf(x2, wa[2].z, acc[i][2]);
            acc[i][3] = fmaf(x2, wa[2].w, acc[i][3]);
            acc[i][4] = fmaf(x2, wb[2].x, acc[i][4]);
            acc[i][5] = fmaf(x2, wb[2].y, acc[i][5]);
            acc[i][6] = fmaf(x2, wb[2].z, acc[i][6]);
            acc[i][7] = fmaf(x2, wb[2].w, acc[i][7]);
            acc[i][0] = fmaf(x3, wa[3].x, acc[i][0]);
            acc[i][1] = fmaf(x3, wa[3].y, acc[i][1]);
            acc[i][2] = fmaf(x3, wa[3].z, acc[i][2]);
            acc[i][3] = fmaf(x3, wa[3].w, acc[i][3]);
            acc[i][4] = fmaf(x3, wb[3].x, acc[i][4]);
            acc[i][5] = fmaf(x3, wb[3].y, acc[i][5]);
            acc[i][6] = fmaf(x3, wb[3].z, acc[i][6]);
            acc[i][7] = fmaf(x3, wb[3].w, acc[i][7]);
        }
    }

    const float4 alA = *(const float4*)&al[cA];
    const float4 alB = *(const float4*)&al[cB];
    const float4 arA = *(const float4*)&ar[cA];
    const float4 arB = *(const float4*)&ar[cB];
    const int hA = tx >> 3;

    #pragma unroll
    for (int i = 0; i < 8; ++i) {
        int r = row0 + i;
        float plA = acc[i][0] * alA.x + acc[i][1] * alA.y + acc[i][2] * alA.z + acc[i][3] * alA.w;
        float prA = acc[i][0] * arA.x + acc[i][1] * arA.y + acc[i][2] * arA.z + acc[i][3] * arA.w;
        float plB = acc[i][4] * alB.x + acc[i][5] * alB.y + acc[i][6] * alB.z + acc[i][7] * alB.w;
        float prB = acc[i][4] * arB.x + acc[i][5] * arB.y + acc[i][6] * arB.z + acc[i][7] * arB.w;
        #pragma unroll
        for (int off = 1; off <= 4; off <<= 1) {
            plA += __shfl_xor(plA, off);
            prA += __shfl_xor(prA, off);
            plB += __shfl_xor(plB, off);
            prB += __shfl_xor(prB, off);
        }
        if ((tx & 7) == 0 && r < NN) {
            el[r * NH + hA]     = plA;
            er[r * NH + hA]     = prA;
            el[r * NH + hA + 2] = plB;
            er[r * NH + hA + 2] = prB;
        }
        if (r < NN) {
            __half2 pA0 = __floats2half2_rn(acc[i][0], acc[i][1]);
            __half2 pA1 = __floats2half2_rn(acc[i][2], acc[i][3]);
            __half2 pB0 = __floats2half2_rn(acc[i][4], acc[i][5]);
            __half2 pB1 = __floats2half2_rn(acc[i][6], acc[i][7]);
            uint2 ua, ub;
            ua.x = *(unsigned*)&pA0; ua.y = *(unsigned*)&pA1;
            ub.x = *(unsigned*)&pB0; ub.y = *(unsigned*)&pB1;
            *(uint2*)&Zh[(size_t)r * HD + cA] = ua;
            *(uint2*)&Zh[(size_t)r * HD + cB] = ub;
        }
    }
}

// ---------------- CSR build (dst-sorted edge list), once per call ----------------
__global__ void k_deg(const int* __restrict__ dst, int* __restrict__ deg) {
    int t = blockIdx.x * blockDim.x + threadIdx.x;
    if (t < NE) atomicAdd(&deg[dst[t]], 1);
}

#define SCAN_B 1024
#define NBLK ((NN + SCAN_B - 1) / SCAN_B)   // 49

// per-block exclusive scan; offs[i] = excl-within-block; bsum[blk] = block total
__global__ __launch_bounds__(1024) void k_scan1(const int* __restrict__ deg,
                                                int* __restrict__ offs,
                                                int* __restrict__ bsum)
{
    __shared__ int wsum[16];
    const int tid = threadIdx.x, lane = tid & 63, w = tid >> 6;
    const int i = blockIdx.x * SCAN_B + tid;
    int v = (i < NN) ? deg[i] : 0;
    int x = v;
    #pragma unroll
    for (int off = 1; off < 64; off <<= 1) {
        int t = __shfl_up(x, off);
        if (lane >= off) x += t;
    }
    if (lane == 63) wsum[w] = x;
    __syncthreads();
    if (w == 0 && lane < 16) {
        int t = wsum[lane];
        #pragma unroll
        for (int off = 1; off < 16; off <<= 1) {
            int u = __shfl_up(t, off);
            if (lane >= off) t += u;
        }
        wsum[lane] = t;   // inclusive scan of wave sums
    }
    __syncthreads();
    int wbase = (w == 0) ? 0 : wsum[w - 1];
    if (i < NN) offs[i] = wbase + x - v;
    if (tid == 0) bsum[blockIdx.x] = wsum[15];
}

// single wave: exclusive scan of 49 block sums (in place); offs[NN] = total
__global__ __launch_bounds__(64) void k_scan2(int* __restrict__ bsum,
                                              int* __restrict__ offs)
{
    const int lane = threadIdx.x;
    int v = (lane < NBLK) ? bsum[lane] : 0;
    int x = v;
    #pragma unroll
    for (int off = 1; off < 64; off <<= 1) {
        int t = __shfl_up(x, off);
        if (lane >= off) x += t;
    }
    if (lane < NBLK) bsum[lane] = x - v;
    if (lane == 63) offs[NN] = x;     // == NE
}

// add block offsets; seed cursor
__global__ __launch_bounds__(1024) void k_scan3(int* __restrict__ offs,
                                                const int* __restrict__ bsum,
                                                int* __restrict__ cursor)
{
    const int i = blockIdx.x * SCAN_B + threadIdx.x;
    if (i < NN) {
        int o = offs[i] + bsum[blockIdx.x];
        offs[i] = o;
        cursor[i] = o;
    }
}

__global__ void k_scatter(const int* __restrict__ src, const int* __restrict__ dst,
                          int* __restrict__ cursor, int* __restrict__ csrc) {
    int t = blockIdx.x * blockDim.x + threadIdx.x;
    if (t < NE) {
        int pos = atomicAdd(&cursor[dst[t]], 1);
        csrc[pos] = src[t];
    }
}

// ---- fused edge softmax + aggregate + finalize: one wave per dst node ----
// No max-shift (softmax is shift-invariant; |e| <= ~10 here, exp safe in fp32)
// -> no serial rescale chain; unroll x4 with independent accumulators.
__global__ __launch_bounds__(256) void k_edge_gat(
    const int* __restrict__ offs, const int* __restrict__ csrc,
    const float* __restrict__ el, const float* __restrict__ er,
    const __half* __restrict__ Zh, const float* __restrict__ b,
    float* __restrict__ X)
{
    int wid = (int)((blockIdx.x * (unsigned)blockDim.x + threadIdx.x) >> 6);
    int lane = threadIdx.x & 63;
    if (wid >= NN) return;
    const int d = wid;
    const int beg = offs[d], end = offs[d + 1];
    const int c0 = lane * 2;
    const int h = lane >> 4;
    const float erd = er[d * NH + h];
    const float2 bb = *(const float2*)&b[c0];

    float s0 = 0.f, s1 = 0.f;
    float a0x = 0.f, a0y = 0.f, a1x = 0.f, a1y = 0.f;
    int i = beg;
    for (; i + 3 < end; i += 4) {
        int sA = csrc[i], sB = csrc[i + 1], sC = csrc[i + 2], sD = csrc[i + 3];
        __half2 zA = *(const __half2*)&Zh[(size_t)sA * HD + c0];
        __half2 zB = *(const __half2*)&Zh[(size_t)sB * HD + c0];
        __half2 zC = *(const __half2*)&Zh[(size_t)sC * HD + c0];
        __half2 zD = *(const __half2*)&Zh[(size_t)sD * HD + c0];
        float eA = el[sA * NH + h] + erd;
        float eB = el[sB * NH + h] + erd;
        float eC = el[sC * NH + h] + erd;
        float eD = el[sD * NH + h] + erd;
        eA = eA >= 0.f ? eA : NEG_SLOPE * eA;
        eB = eB >= 0.f ? eB : NEG_SLOPE * eB;
        eC = eC >= 0.f ? eC : NEG_SLOPE * eC;
        eD = eD >= 0.f ? eD : NEG_SLOPE * eD;
        float pA = __expf(eA), pB = __expf(eB), pC = __expf(eC), pD = __expf(eD);
        float2 fA = __half22float2(zA);
        float2 fB = __half22float2(zB);
        float2 fC = __half22float2(zC);
        float2 fD = __half22float2(zD);
        s0 += pA + pB;
        s1 += pC + pD;
        a0x = fmaf(fA.x, pA, a0x); a0y = fmaf(fA.y, pA, a0y);
        a1x = fmaf(fB.x, pB, a1x); a1y = fmaf(fB.y, pB, a1y);
        a0x = fmaf(fC.x, pC, a0x); a0y = fmaf(fC.y, pC, a0y);
        a1x = fmaf(fD.x, pD, a1x); a1y = fmaf(fD.y, pD, a1y);
    }
    for (; i < end; ++i) {
        int s = csrc[i];
        __half2 zh = *(const __half2*)&Zh[(size_t)s * HD + c0];
        float e = el[s * NH + h] + erd;
        e = e >= 0.f ? e : NEG_SLOPE * e;
        float p = __expf(e);
        float2 f = __half22float2(zh);
        s0 += p;
        a0x = fmaf(f.x, p, a0x);
        a0y = fmaf(f.y, p, a0y);
    }
    float sden = s0 + s1;
    float ax = a0x + a1x, ay = a0y + a1y;
    float inv = (end > beg) ? 1.f / sden : 0.f;
    float v0 = ax * inv + bb.x;
    float v1 = ay * inv + bb.y;
    float2 o;
    o.x = v0 > 0.f ? v0 : 0.f;
    o.y = v1 > 0.f ? v1 : 0.f;
    *(float2*)&X[(size_t)d * HD + c0] = o;
}

// ---- fused mean-pool + classifier: one 1024-thread block per graph ----
__global__ __launch_bounds__(1024) void k_pool_classify(
    const float* __restrict__ X, const int* __restrict__ gid,
    const float* __restrict__ Wc, const float* __restrict__ bc,
    float* __restrict__ out)
{
    __shared__ float part[8][HD];
    __shared__ float shg[HD];
    __shared__ int slo, shi;
    const int g = blockIdx.x;
    const int tid = threadIdx.x;
    const int c = tid & 127;
    const int gr = tid >> 7;            // 8 row-groups
    if (tid == 0) {
        int lo = 0, hi = NN;
        while (lo < hi) { int mid = (lo + hi) >> 1; if (gid[mid] < g) lo = mid + 1; else hi = mid; }
        slo = lo;
        int lo2 = lo; hi = NN;
        while (lo2 < hi) { int mid = (lo2 + hi) >> 1; if (gid[mid] < g + 1) lo2 = mid + 1; else hi = mid; }
        shi = lo2;
    }
    __syncthreads();
    const int lo = slo, hi = shi;
    float acc = 0.f;
    for (int n = lo + gr; n < hi; n += 8) acc += X[(size_t)n * HD + c];
    part[gr][c] = acc;
    __syncthreads();
    if (gr == 0) {
        float s = part[0][c] + part[1][c] + part[2][c] + part[3][c]
                + part[4][c] + part[5][c] + part[6][c] + part[7][c];
        shg[c] = s / fmaxf((float)(hi - lo), 1.f);
    }
    __syncthreads();
    if (tid < NC) {
        float r = bc[tid];
        #pragma unroll
        for (int k = 0; k < HD; ++k) r = fmaf(shg[k], Wc[k * NC + tid], r);
        out[g * NC + tid] = r;
    }
}

extern "C" void kernel_launch(void* const* d_in, const int* in_sizes, int n_in,
                              void* d_out, int out_size, void* d_ws, size_t ws_size,
                              hipStream_t stream) {
    const float* h    = (const float*)d_in[0];
    const int*   src  = (const int*)  d_in[1];
    const int*   dst  = (const int*)  d_in[2];
    const int*   gid  = (const int*)  d_in[3];
    const float* W1   = (const float*)d_in[4];
    const float* al1  = (const float*)d_in[5];
    const float* ar1  = (const float*)d_in[6];
    const float* b1   = (const float*)d_in[7];
    const float* W2   = (const float*)d_in[8];
    const float* al2  = (const float*)d_in[9];
    const float* ar2  = (const float*)d_in[10];
    const float* b2   = (const float*)d_in[11];
    const float* Wc   = (const float*)d_in[12];
    const float* bc   = (const float*)d_in[13];
    float* out = (float*)d_out;

    char* w = (char*)d_ws;
    __half* zh  = (__half*)w; w += (size_t)NN * HD * 2;   // 12.8 MB
    float* xb   = (float*)w;  w += (size_t)NN * HD * 4;   // 25.6 MB
    float* el   = (float*)w;  w += (size_t)NN * NH * 4;
    float* er   = (float*)w;  w += (size_t)NN * NH * 4;
    int*   deg  = (int*)w;    w += (size_t)NN * 4;
    int*   offs = (int*)w;    w += (size_t)(NN + 1) * 4;
    int*   curs = (int*)w;    w += (size_t)NN * 4;
    int*   bsum = (int*)w;    w += (size_t)NBLK * 4;
    int*   csrc = (int*)w;    w += (size_t)NE * 4;        // 3.2 MB

    const int TB = 256;
    const int gE    = (NE + TB - 1) / TB;
    const int gGemm = (NN + BM - 1) / BM;        // 391
    const int gEdge = (NN * 64 + TB - 1) / TB;   // one wave per dst

    // ---------------- CSR build (dst constant across layers) ----------------
    hipMemsetAsync(deg, 0, (size_t)NN * 4, stream);
    k_deg<<<gE, TB, 0, stream>>>(dst, deg);
    k_scan1<<<NBLK, SCAN_B, 0, stream>>>(deg, offs, bsum);
    k_scan2<<<1, 64, 0, stream>>>(bsum, offs);
    k_scan3<<<NBLK, SCAN_B, 0, stream>>>(offs, bsum, curs);
    k_scatter<<<gE, TB, 0, stream>>>(src, dst, curs, csrc);

    // ---------------- layer 1 ----------------
    k_gemm_attn<<<gGemm, 256, 0, stream>>>(h, W1, al1, ar1, zh, el, er);
    k_edge_gat<<<gEdge, TB, 0, stream>>>(offs, csrc, el, er, zh, b1, xb);

    // ---------------- layer 2 ----------------
    k_gemm_attn<<<gGemm, 256, 0, stream>>>(xb, W2, al2, ar2, zh, el, er);
    k_edge_gat<<<gEdge, TB, 0, stream>>>(offs, csrc, el, er, zh, b2, xb);

    // ---------------- fused pooling + classifier ----------------
    k_pool_classify<<<NG, 1024, 0, stream>>>(xb, gid, Wc, bc, out);
}

// Round 9
// 308.985 us; speedup vs baseline: 5.6263x; 1.1424x over previous
//
#include <hip/hip_runtime.h>
#include <hip/hip_fp16.h>
#include <math.h>

#define NN 50000      // nodes
#define NE 800000     // edges
#define NG 128        // graphs
#define HD 128        // H*D
#define NH 4          // heads
#define NC 10         // classes
#define NEG_SLOPE 0.2f

// ---- register-tiled GEMM (x[N,128] @ W[128,128]) fused with el/er logits ----
#define BM 128
__global__ __launch_bounds__(256, 2) void k_gemm_attn(
    const float* __restrict__ X, const float* __restrict__ W,
    const float* __restrict__ al, const float* __restrict__ ar,
    __half* __restrict__ Zh, float* __restrict__ el, float* __restrict__ er)
{
    __shared__ float Ws[HD * HD];   // 64 KiB, [k][col]
    const int tid = threadIdx.x;
    {
        const float4* Wg = (const float4*)W;
        float4* Wl = (float4*)Ws;
        #pragma unroll
        for (int i = 0; i < 16; ++i) Wl[i * 256 + tid] = Wg[i * 256 + tid];
    }
    const int tx = tid & 15, ty = tid >> 4;
    const int cA = 4 * tx;          // head hA = tx>>3 (0/1)
    const int cB = 64 + 4 * tx;     // head hA+2
    const int row0 = blockIdx.x * BM + ty * 8;

    int rows[8];
    #pragma unroll
    for (int i = 0; i < 8; ++i) {
        int r = row0 + i;
        rows[i] = r < NN ? r : NN - 1;   // clamp; stores guarded later
    }

    float acc[8][8];
    #pragma unroll
    for (int i = 0; i < 8; ++i)
        #pragma unroll
        for (int j = 0; j < 8; ++j) acc[i][j] = 0.f;

    __syncthreads();

    #pragma unroll 2
    for (int k0 = 0; k0 < HD; k0 += 4) {
        float4 xv[8];
        #pragma unroll
        for (int i = 0; i < 8; ++i)
            xv[i] = *(const float4*)&X[(size_t)rows[i] * HD + k0];
        float4 wa[4], wb[4];
        #pragma unroll
        for (int kk = 0; kk < 4; ++kk) {
            wa[kk] = *(const float4*)&Ws[(k0 + kk) * HD + cA];
            wb[kk] = *(const float4*)&Ws[(k0 + kk) * HD + cB];
        }
        #pragma unroll
        for (int i = 0; i < 8; ++i) {
            float x0 = xv[i].x, x1 = xv[i].y, x2 = xv[i].z, x3 = xv[i].w;
            acc[i][0] = fmaf(x0, wa[0].x, acc[i][0]);
            acc[i][1] = fmaf(x0, wa[0].y, acc[i][1]);
            acc[i][2] = fmaf(x0, wa[0].z, acc[i][2]);
            acc[i][3] = fmaf(x0, wa[0].w, acc[i][3]);
            acc[i][4] = fmaf(x0, wb[0].x, acc[i][4]);
            acc[i][5] = fmaf(x0, wb[0].y, acc[i][5]);
            acc[i][6] = fmaf(x0, wb[0].z, acc[i][6]);
            acc[i][7] = fmaf(x0, wb[0].w, acc[i][7]);
            acc[i][0] = fmaf(x1, wa[1].x, acc[i][0]);
            acc[i][1] = fmaf(x1, wa[1].y, acc[i][1]);
            acc[i][2] = fmaf(x1, wa[1].z, acc[i][2]);
            acc[i][3] = fmaf(x1, wa[1].w, acc[i][3]);
            acc[i][4] = fmaf(x1, wb[1].x, acc[i][4]);
            acc[i][5] = fmaf(x1, wb[1].y, acc[i][5]);
            acc[i][6] = fmaf(x1, wb[1].z, acc[i][6]);
            acc[i][7] = fmaf(x1, wb[1].w, acc[i][7]);
            acc[i][0] = fmaf(x2, wa[2].x, acc[i][0]);
            acc[i][1] = fmaf(x2, wa[2].y, acc[i][1]);
            acc[i][2] = fmaf(x2, wa[2].z, acc[i][2]);
            acc[i][3] = fmaf(x2, wa[2].w, acc[i][3]);
            acc[i][4] = fmaf(x2, wb[2].x, acc[i][4]);
            acc[i][5] = fmaf(x2, wb[2].y, acc[i][5]);
            acc[i][6] = fmaf(x2, wb[2].z, acc[i][6]);
            acc[i][7] = fmaf(x2, wb[2].w, acc[i][7]);
            acc[i][0] = fmaf(x3, wa[3].x, acc[i][0]);
            acc[i][1] = fmaf(x3, wa[3].y, acc[i][1]);
            acc[i][2] = fmaf(x3, wa[3].z, acc[i][2]);
            acc[i][3] = fmaf(x3, wa[3].w, acc[i][3]);
            acc[i][4] = fmaf(x3, wb[3].x, acc[i][4]);
            acc[i][5] = fmaf(x3, wb[3].y, acc[i][5]);
            acc[i][6] = fmaf(x3, wb[3].z, acc[i][6]);
            acc[i][7] = fmaf(x3, wb[3].w, acc[i][7]);
        }
    }

    const float4 alA = *(const float4*)&al[cA];
    const float4 alB = *(const float4*)&al[cB];
    const float4 arA = *(const float4*)&ar[cA];
    const float4 arB = *(const float4*)&ar[cB];
    const int hA = tx >> 3;

    #pragma unroll
    for (int i = 0; i < 8; ++i) {
        int r = row0 + i;
        float plA = acc[i][0] * alA.x + acc[i][1] * alA.y + acc[i][2] * alA.z + acc[i][3] * alA.w;
        float prA = acc[i][0] * arA.x + acc[i][1] * arA.y + acc[i][2] * arA.z + acc[i][3] * arA.w;
        float plB = acc[i][4] * alB.x + acc[i][5] * alB.y + acc[i][6] * alB.z + acc[i][7] * alB.w;
        float prB = acc[i][4] * arB.x + acc[i][5] * arB.y + acc[i][6] * arB.z + acc[i][7] * arB.w;
        #pragma unroll
        for (int off = 1; off <= 4; off <<= 1) {
            plA += __shfl_xor(plA, off);
            prA += __shfl_xor(prA, off);
            plB += __shfl_xor(plB, off);
            prB += __shfl_xor(prB, off);
        }
        if ((tx & 7) == 0 && r < NN) {
            el[r * NH + hA]     = plA;
            er[r * NH + hA]     = prA;
            el[r * NH + hA + 2] = plB;
            er[r * NH + hA + 2] = prB;
        }
        if (r < NN) {
            __half2 pA0 = __floats2half2_rn(acc[i][0], acc[i][1]);
            __half2 pA1 = __floats2half2_rn(acc[i][2], acc[i][3]);
            __half2 pB0 = __floats2half2_rn(acc[i][4], acc[i][5]);
            __half2 pB1 = __floats2half2_rn(acc[i][6], acc[i][7]);
            uint2 ua, ub;
            ua.x = *(unsigned*)&pA0; ua.y = *(unsigned*)&pA1;
            ub.x = *(unsigned*)&pB0; ub.y = *(unsigned*)&pB1;
            *(uint2*)&Zh[(size_t)r * HD + cA] = ua;
            *(uint2*)&Zh[(size_t)r * HD + cB] = ub;
        }
    }
}

// ---------------- CSR build (dst-sorted edge list), once per call ----------------
// deg pass also records each edge's within-segment rank (atomicAdd return value),
// so the scatter pass needs NO atomics.
__global__ void k_deg(const int* __restrict__ dst, int* __restrict__ deg,
                      int* __restrict__ rank) {
    int t = blockIdx.x * blockDim.x + threadIdx.x;
    if (t < NE) rank[t] = atomicAdd(&deg[dst[t]], 1);
}

#define SCAN_B 1024
#define NBLK ((NN + SCAN_B - 1) / SCAN_B)   // 49

// per-block exclusive scan; offs[i] = excl-within-block; bsum[blk] = block total
__global__ __launch_bounds__(1024) void k_scan1(const int* __restrict__ deg,
                                                int* __restrict__ offs,
                                                int* __restrict__ bsum)
{
    __shared__ int wsum[16];
    const int tid = threadIdx.x, lane = tid & 63, w = tid >> 6;
    const int i = blockIdx.x * SCAN_B + tid;
    int v = (i < NN) ? deg[i] : 0;
    int x = v;
    #pragma unroll
    for (int off = 1; off < 64; off <<= 1) {
        int t = __shfl_up(x, off);
        if (lane >= off) x += t;
    }
    if (lane == 63) wsum[w] = x;
    __syncthreads();
    if (w == 0 && lane < 16) {
        int t = wsum[lane];
        #pragma unroll
        for (int off = 1; off < 16; off <<= 1) {
            int u = __shfl_up(t, off);
            if (lane >= off) t += u;
        }
        wsum[lane] = t;   // inclusive scan of wave sums
    }
    __syncthreads();
    int wbase = (w == 0) ? 0 : wsum[w - 1];
    if (i < NN) offs[i] = wbase + x - v;
    if (tid == 0) bsum[blockIdx.x] = wsum[15];
}

// single wave: exclusive scan of 49 block sums (in place); offs[NN] = total
__global__ __launch_bounds__(64) void k_scan2(int* __restrict__ bsum,
                                              int* __restrict__ offs)
{
    const int lane = threadIdx.x;
    int v = (lane < NBLK) ? bsum[lane] : 0;
    int x = v;
    #pragma unroll
    for (int off = 1; off < 64; off <<= 1) {
        int t = __shfl_up(x, off);
        if (lane >= off) x += t;
    }
    if (lane < NBLK) bsum[lane] = x - v;
    if (lane == 63) offs[NN] = x;     // == NE
}

// add block offsets
__global__ __launch_bounds__(1024) void k_scan3(int* __restrict__ offs,
                                                const int* __restrict__ bsum)
{
    const int i = blockIdx.x * SCAN_B + threadIdx.x;
    if (i < NN) offs[i] += bsum[blockIdx.x];
}

// atomic-free scatter: position = offs[dst] + rank  (rank from k_deg)
__global__ void k_scatter(const int* __restrict__ src, const int* __restrict__ dst,
                          const int* __restrict__ rank, const int* __restrict__ offs,
                          int* __restrict__ csrc) {
    int t = blockIdx.x * blockDim.x + threadIdx.x;
    if (t < NE) {
        csrc[offs[dst[t]] + rank[t]] = src[t];
    }
}

// ---- fused edge softmax + aggregate + finalize: one wave per dst node ----
// No max-shift (softmax is shift-invariant; |e| <= ~10 here, exp safe in fp32)
// -> no serial rescale chain; unroll x4 with independent accumulators.
__global__ __launch_bounds__(256) void k_edge_gat(
    const int* __restrict__ offs, const int* __restrict__ csrc,
    const float* __restrict__ el, const float* __restrict__ er,
    const __half* __restrict__ Zh, const float* __restrict__ b,
    float* __restrict__ X)
{
    int wid = (int)((blockIdx.x * (unsigned)blockDim.x + threadIdx.x) >> 6);
    int lane = threadIdx.x & 63;
    if (wid >= NN) return;
    const int d = wid;
    const int beg = offs[d], end = offs[d + 1];
    const int c0 = lane * 2;
    const int h = lane >> 4;
    const float erd = er[d * NH + h];
    const float2 bb = *(const float2*)&b[c0];

    float s0 = 0.f, s1 = 0.f;
    float a0x = 0.f, a0y = 0.f, a1x = 0.f, a1y = 0.f;
    int i = beg;
    for (; i + 3 < end; i += 4) {
        int sA = csrc[i], sB = csrc[i + 1], sC = csrc[i + 2], sD = csrc[i + 3];
        __half2 zA = *(const __half2*)&Zh[(size_t)sA * HD + c0];
        __half2 zB = *(const __half2*)&Zh[(size_t)sB * HD + c0];
        __half2 zC = *(const __half2*)&Zh[(size_t)sC * HD + c0];
        __half2 zD = *(const __half2*)&Zh[(size_t)sD * HD + c0];
        float eA = el[sA * NH + h] + erd;
        float eB = el[sB * NH + h] + erd;
        float eC = el[sC * NH + h] + erd;
        float eD = el[sD * NH + h] + erd;
        eA = eA >= 0.f ? eA : NEG_SLOPE * eA;
        eB = eB >= 0.f ? eB : NEG_SLOPE * eB;
        eC = eC >= 0.f ? eC : NEG_SLOPE * eC;
        eD = eD >= 0.f ? eD : NEG_SLOPE * eD;
        float pA = __expf(eA), pB = __expf(eB), pC = __expf(eC), pD = __expf(eD);
        float2 fA = __half22float2(zA);
        float2 fB = __half22float2(zB);
        float2 fC = __half22float2(zC);
        float2 fD = __half22float2(zD);
        s0 += pA + pB;
        s1 += pC + pD;
        a0x = fmaf(fA.x, pA, a0x); a0y = fmaf(fA.y, pA, a0y);
        a1x = fmaf(fB.x, pB, a1x); a1y = fmaf(fB.y, pB, a1y);
        a0x = fmaf(fC.x, pC, a0x); a0y = fmaf(fC.y, pC, a0y);
        a1x = fmaf(fD.x, pD, a1x); a1y = fmaf(fD.y, pD, a1y);
    }
    for (; i < end; ++i) {
        int s = csrc[i];
        __half2 zh = *(const __half2*)&Zh[(size_t)s * HD + c0];
        float e = el[s * NH + h] + erd;
        e = e >= 0.f ? e : NEG_SLOPE * e;
        float p = __expf(e);
        float2 f = __half22float2(zh);
        s0 += p;
        a0x = fmaf(f.x, p, a0x);
        a0y = fmaf(f.y, p, a0y);
    }
    float sden = s0 + s1;
    float ax = a0x + a1x, ay = a0y + a1y;
    float inv = (end > beg) ? 1.f / sden : 0.f;
    float v0 = ax * inv + bb.x;
    float v1 = ay * inv + bb.y;
    float2 o;
    o.x = v0 > 0.f ? v0 : 0.f;
    o.y = v1 > 0.f ? v1 : 0.f;
    *(float2*)&X[(size_t)d * HD + c0] = o;
}

// ---- fused mean-pool + classifier: one 1024-thread block per graph ----
__global__ __launch_bounds__(1024) void k_pool_classify(
    const float* __restrict__ X, const int* __restrict__ gid,
    const float* __restrict__ Wc, const float* __restrict__ bc,
    float* __restrict__ out)
{
    __shared__ float part[8][HD];
    __shared__ float shg[HD];
    __shared__ int slo, shi;
    const int g = blockIdx.x;
    const int tid = threadIdx.x;
    const int c = tid & 127;
    const int gr = tid >> 7;            // 8 row-groups
    if (tid == 0) {
        int lo = 0, hi = NN;
        while (lo < hi) { int mid = (lo + hi) >> 1; if (gid[mid] < g) lo = mid + 1; else hi = mid; }
        slo = lo;
        int lo2 = lo; hi = NN;
        while (lo2 < hi) { int mid = (lo2 + hi) >> 1; if (gid[mid] < g + 1) lo2 = mid + 1; else hi = mid; }
        shi = lo2;
    }
    __syncthreads();
    const int lo = slo, hi = shi;
    float acc = 0.f;
    for (int n = lo + gr; n < hi; n += 8) acc += X[(size_t)n * HD + c];
    part[gr][c] = acc;
    __syncthreads();
    if (gr == 0) {
        float s = part[0][c] + part[1][c] + part[2][c] + part[3][c]
                + part[4][c] + part[5][c] + part[6][c] + part[7][c];
        shg[c] = s / fmaxf((float)(hi - lo), 1.f);
    }
    __syncthreads();
    if (tid < NC) {
        float r = bc[tid];
        #pragma unroll
        for (int k = 0; k < HD; ++k) r = fmaf(shg[k], Wc[k * NC + tid], r);
        out[g * NC + tid] = r;
    }
}

extern "C" void kernel_launch(void* const* d_in, const int* in_sizes, int n_in,
                              void* d_out, int out_size, void* d_ws, size_t ws_size,
                              hipStream_t stream) {
    const float* h    = (const float*)d_in[0];
    const int*   src  = (const int*)  d_in[1];
    const int*   dst  = (const int*)  d_in[2];
    const int*   gid  = (const int*)  d_in[3];
    const float* W1   = (const float*)d_in[4];
    const float* al1  = (const float*)d_in[5];
    const float* ar1  = (const float*)d_in[6];
    const float* b1   = (const float*)d_in[7];
    const float* W2   = (const float*)d_in[8];
    const float* al2  = (const float*)d_in[9];
    const float* ar2  = (const float*)d_in[10];
    const float* b2   = (const float*)d_in[11];
    const float* Wc   = (const float*)d_in[12];
    const float* bc   = (const float*)d_in[13];
    float* out = (float*)d_out;

    char* w = (char*)d_ws;
    __half* zh  = (__half*)w; w += (size_t)NN * HD * 2;   // 12.8 MB
    float* xb   = (float*)w;  w += (size_t)NN * HD * 4;   // 25.6 MB
    float* el   = (float*)w;  w += (size_t)NN * NH * 4;
    float* er   = (float*)w;  w += (size_t)NN * NH * 4;
    int*   deg  = (int*)w;    w += (size_t)NN * 4;
    int*   offs = (int*)w;    w += (size_t)(NN + 1) * 4;
    int*   bsum = (int*)w;    w += (size_t)NBLK * 4;
    int*   rank = (int*)w;    w += (size_t)NE * 4;        // 3.2 MB
    int*   csrc = (int*)w;    w += (size_t)NE * 4;        // 3.2 MB

    const int TB = 256;
    const int gE    = (NE + TB - 1) / TB;
    const int gGemm = (NN + BM - 1) / BM;        // 391
    const int gEdge = (NN * 64 + TB - 1) / TB;   // one wave per dst

    // ---------------- CSR build (dst constant across layers) ----------------
    hipMemsetAsync(deg, 0, (size_t)NN * 4, stream);
    k_deg<<<gE, TB, 0, stream>>>(dst, deg, rank);
    k_scan1<<<NBLK, SCAN_B, 0, stream>>>(deg, offs, bsum);
    k_scan2<<<1, 64, 0, stream>>>(bsum, offs);
    k_scan3<<<NBLK, SCAN_B, 0, stream>>>(offs, bsum);
    k_scatter<<<gE, TB, 0, stream>>>(src, dst, rank, offs, csrc);

    // ---------------- layer 1 ----------------
    k_gemm_attn<<<gGemm, 256, 0, stream>>>(h, W1, al1, ar1, zh, el, er);
    k_edge_gat<<<gEdge, TB, 0, stream>>>(offs, csrc, el, er, zh, b1, xb);

    // ---------------- layer 2 ----------------
    k_gemm_attn<<<gGemm, 256, 0, stream>>>(xb, W2, al2, ar2, zh, el, er);
    k_edge_gat<<<gEdge, TB, 0, stream>>>(offs, csrc, el, er, zh, b2, xb);

    // ---------------- fused pooling + classifier ----------------
    k_pool_classify<<<NG, 1024, 0, stream>>>(xb, gid, Wc, bc, out);
}

// Round 11
// 303.538 us; speedup vs baseline: 5.7272x; 1.0179x over previous
//
#include <hip/hip_runtime.h>
#include <hip/hip_fp16.h>
#include <math.h>

#define NN 50000      // nodes
#define NE 800000     // edges
#define NG 128        // graphs
#define HD 128        // H*D
#define NH 4          // heads
#define NC 10         // classes
#define NEG_SLOPE 0.2f

typedef _Float16 f16x8 __attribute__((ext_vector_type(8)));
typedef float    f32x4 __attribute__((ext_vector_type(4)));

// ---- MFMA fp16 GEMM (x[N,128] @ W[128,128]) fused with el/er logits ----
// 4 waves/block, each wave computes 16 rows x 128 cols via 8 n-tiles of
// mfma_f32_16x16x32_f16. W repacked per-block into LDS in B-fragment order
// (lane l supplies W[kt*32+(l>>4)*8+j][nt*16+(l&15)], j=0..7 -> k-map identical
// to the A fragment, so the contraction is k-order invariant).
// C/D layout (HW-verified): col = lane&15, row = (lane>>4)*4 + j.
#define GROWS 64
__global__ __launch_bounds__(256, 2) void k_gemm_attn(
    const float* __restrict__ X, const float* __restrict__ W,
    const float* __restrict__ al, const float* __restrict__ ar,
    __half* __restrict__ Zh, float* __restrict__ el, float* __restrict__ er)
{
    __shared__ __align__(16) _Float16 Wp[4][8][64][8];   // 32 KiB
    const int tid = threadIdx.x;
    // repack W (fp32 [k][n] row-major) -> fragment order
    for (int idx = tid; idx < 128 * 32; idx += 256) {
        int k = idx >> 5, n4 = idx & 31;
        float4 wv = *(const float4*)&W[k * HD + n4 * 4];
        int kt = k >> 5, kin = k & 31;
        int kg = kin >> 3, j = kin & 7;
        #pragma unroll
        for (int q = 0; q < 4; ++q) {
            int n = n4 * 4 + q;
            float v = (q == 0) ? wv.x : (q == 1) ? wv.y : (q == 2) ? wv.z : wv.w;
            Wp[kt][n >> 4][kg * 16 + (n & 15)][j] = (_Float16)v;
        }
    }
    const int w = tid >> 6, l = tid & 63;
    const int l15 = l & 15, lg = l >> 4;
    const int rbase = blockIdx.x * GROWS + w * 16;
    int arow = rbase + l15;                  // row this lane loads (A m-index)
    int arow_c = arow < NN ? arow : NN - 1;  // clamp; C-row stores guarded
    __syncthreads();

    f32x4 acc[8];
    #pragma unroll
    for (int nt = 0; nt < 8; ++nt) acc[nt] = (f32x4)(0.f);

    #pragma unroll
    for (int kt = 0; kt < 4; ++kt) {
        const float* xp = &X[(size_t)arow_c * HD + kt * 32 + lg * 8];
        float4 x0 = *(const float4*)xp;
        float4 x1 = *(const float4*)(xp + 4);
        f16x8 afrag;
        afrag[0] = (_Float16)x0.x; afrag[1] = (_Float16)x0.y;
        afrag[2] = (_Float16)x0.z; afrag[3] = (_Float16)x0.w;
        afrag[4] = (_Float16)x1.x; afrag[5] = (_Float16)x1.y;
        afrag[6] = (_Float16)x1.z; afrag[7] = (_Float16)x1.w;
        #pragma unroll
        for (int nt = 0; nt < 8; ++nt) {
            f16x8 bfrag = *(const f16x8*)&Wp[kt][nt][l][0];
            acc[nt] = __builtin_amdgcn_mfma_f32_16x16x32_f16(afrag, bfrag, acc[nt], 0, 0, 0);
        }
    }

    // epilogue: el/er partials over this lane's column, reduce across 16 col-lanes
    float alv[8], arv[8];
    #pragma unroll
    for (int nt = 0; nt < 8; ++nt) {
        alv[nt] = al[nt * 16 + l15];
        arv[nt] = ar[nt * 16 + l15];
    }
    float pl[4][4], pr[4][4];   // [j][h]
    #pragma unroll
    for (int j = 0; j < 4; ++j)
        #pragma unroll
        for (int h = 0; h < 4; ++h) {
            pl[j][h] = acc[2*h][j] * alv[2*h] + acc[2*h+1][j] * alv[2*h+1];
            pr[j][h] = acc[2*h][j] * arv[2*h] + acc[2*h+1][j] * arv[2*h+1];
        }
    #pragma unroll
    for (int off = 1; off <= 8; off <<= 1)
        #pragma unroll
        for (int j = 0; j < 4; ++j)
            #pragma unroll
            for (int h = 0; h < 4; ++h) {
                pl[j][h] += __shfl_xor(pl[j][h], off);
                pr[j][h] += __shfl_xor(pr[j][h], off);
            }
    if (l15 == 0) {
        #pragma unroll
        for (int j = 0; j < 4; ++j) {
            int r = rbase + lg * 4 + j;
            if (r < NN) {
                *(float4*)&el[(size_t)r * NH] = make_float4(pl[j][0], pl[j][1], pl[j][2], pl[j][3]);
                *(float4*)&er[(size_t)r * NH] = make_float4(pr[j][0], pr[j][1], pr[j][2], pr[j][3]);
            }
        }
    }
    // z store (fp16): row = rbase + lg*4 + j, col = nt*16 + l15
    #pragma unroll
    for (int j = 0; j < 4; ++j) {
        int r = rbase + lg * 4 + j;
        if (r < NN) {
            #pragma unroll
            for (int nt = 0; nt < 8; ++nt)
                Zh[(size_t)r * HD + nt * 16 + l15] = __float2half(acc[nt][j]);
        }
    }
}

// ---------------- CSR build (dst-sorted edge list), once per call ----------------
// deg pass also records each edge's within-segment rank (atomicAdd return value),
// so the scatter pass needs NO atomics.
__global__ void k_deg(const int* __restrict__ dst, int* __restrict__ deg,
                      int* __restrict__ rank) {
    int t = blockIdx.x * blockDim.x + threadIdx.x;
    if (t < NE) rank[t] = atomicAdd(&deg[dst[t]], 1);
}

#define SCAN_B 1024
#define NBLK ((NN + SCAN_B - 1) / SCAN_B)   // 49

__global__ __launch_bounds__(1024) void k_scan1(const int* __restrict__ deg,
                                                int* __restrict__ offs,
                                                int* __restrict__ bsum)
{
    __shared__ int wsum[16];
    const int tid = threadIdx.x, lane = tid & 63, w = tid >> 6;
    const int i = blockIdx.x * SCAN_B + tid;
    int v = (i < NN) ? deg[i] : 0;
    int x = v;
    #pragma unroll
    for (int off = 1; off < 64; off <<= 1) {
        int t = __shfl_up(x, off);
        if (lane >= off) x += t;
    }
    if (lane == 63) wsum[w] = x;
    __syncthreads();
    if (w == 0 && lane < 16) {
        int t = wsum[lane];
        #pragma unroll
        for (int off = 1; off < 16; off <<= 1) {
            int u = __shfl_up(t, off);
            if (lane >= off) t += u;
        }
        wsum[lane] = t;
    }
    __syncthreads();
    int wbase = (w == 0) ? 0 : wsum[w - 1];
    if (i < NN) offs[i] = wbase + x - v;
    if (tid == 0) bsum[blockIdx.x] = wsum[15];
}

__global__ __launch_bounds__(64) void k_scan2(int* __restrict__ bsum,
                                              int* __restrict__ offs)
{
    const int lane = threadIdx.x;
    int v = (lane < NBLK) ? bsum[lane] : 0;
    int x = v;
    #pragma unroll
    for (int off = 1; off < 64; off <<= 1) {
        int t = __shfl_up(x, off);
        if (lane >= off) x += t;
    }
    if (lane < NBLK) bsum[lane] = x - v;
    if (lane == 63) offs[NN] = x;     // == NE
}

__global__ __launch_bounds__(1024) void k_scan3(int* __restrict__ offs,
                                                const int* __restrict__ bsum)
{
    const int i = blockIdx.x * SCAN_B + threadIdx.x;
    if (i < NN) offs[i] += bsum[blockIdx.x];
}

// atomic-free scatter: position = offs[dst] + rank  (rank from k_deg)
__global__ void k_scatter(const int* __restrict__ src, const int* __restrict__ dst,
                          const int* __restrict__ rank, const int* __restrict__ offs,
                          int* __restrict__ csrc) {
    int t = blockIdx.x * blockDim.x + threadIdx.x;
    if (t < NE) {
        csrc[offs[dst[t]] + rank[t]] = src[t];
    }
}

// ---- fused edge softmax + aggregate + finalize: one wave per dst node ----
__global__ __launch_bounds__(256) void k_edge_gat(
    const int* __restrict__ offs, const int* __restrict__ csrc,
    const float* __restrict__ el, const float* __restrict__ er,
    const __half* __restrict__ Zh, const float* __restrict__ b,
    float* __restrict__ X)
{
    int wid = (int)((blockIdx.x * (unsigned)blockDim.x + threadIdx.x) >> 6);
    int lane = threadIdx.x & 63;
    if (wid >= NN) return;
    const int d = wid;
    const int beg = offs[d], end = offs[d + 1];
    const int c0 = lane * 2;
    const int h = lane >> 4;
    const float erd = er[d * NH + h];
    const float2 bb = *(const float2*)&b[c0];

    float s0 = 0.f, s1 = 0.f;
    float a0x = 0.f, a0y = 0.f, a1x = 0.f, a1y = 0.f;
    int i = beg;
    for (; i + 3 < end; i += 4) {
        int sA = csrc[i], sB = csrc[i + 1], sC = csrc[i + 2], sD = csrc[i + 3];
        __half2 zA = *(const __half2*)&Zh[(size_t)sA * HD + c0];
        __half2 zB = *(const __half2*)&Zh[(size_t)sB * HD + c0];
        __half2 zC = *(const __half2*)&Zh[(size_t)sC * HD + c0];
        __half2 zD = *(const __half2*)&Zh[(size_t)sD * HD + c0];
        float eA = el[sA * NH + h] + erd;
        float eB = el[sB * NH + h] + erd;
        float eC = el[sC * NH + h] + erd;
        float eD = el[sD * NH + h] + erd;
        eA = eA >= 0.f ? eA : NEG_SLOPE * eA;
        eB = eB >= 0.f ? eB : NEG_SLOPE * eB;
        eC = eC >= 0.f ? eC : NEG_SLOPE * eC;
        eD = eD >= 0.f ? eD : NEG_SLOPE * eD;
        float pA = __expf(eA), pB = __expf(eB), pC = __expf(eC), pD = __expf(eD);
        float2 fA = __half22float2(zA);
        float2 fB = __half22float2(zB);
        float2 fC = __half22float2(zC);
        float2 fD = __half22float2(zD);
        s0 += pA + pB;
        s1 += pC + pD;
        a0x = fmaf(fA.x, pA, a0x); a0y = fmaf(fA.y, pA, a0y);
        a1x = fmaf(fB.x, pB, a1x); a1y = fmaf(fB.y, pB, a1y);
        a0x = fmaf(fC.x, pC, a0x); a0y = fmaf(fC.y, pC, a0y);
        a1x = fmaf(fD.x, pD, a1x); a1y = fmaf(fD.y, pD, a1y);
    }
    for (; i < end; ++i) {
        int s = csrc[i];
        __half2 zh = *(const __half2*)&Zh[(size_t)s * HD + c0];
        float e = el[s * NH + h] + erd;
        e = e >= 0.f ? e : NEG_SLOPE * e;
        float p = __expf(e);
        float2 f = __half22float2(zh);
        s0 += p;
        a0x = fmaf(f.x, p, a0x);
        a0y = fmaf(f.y, p, a0y);
    }
    float sden = s0 + s1;
    float ax = a0x + a1x, ay = a0y + a1y;
    float inv = (end > beg) ? 1.f / sden : 0.f;
    float v0 = ax * inv + bb.x;
    float v1 = ay * inv + bb.y;
    float2 o;
    o.x = v0 > 0.f ? v0 : 0.f;
    o.y = v1 > 0.f ? v1 : 0.f;
    *(float2*)&X[(size_t)d * HD + c0] = o;
}

// ---- fused mean-pool + classifier: one 1024-thread block per graph ----
__global__ __launch_bounds__(1024) void k_pool_classify(
    const float* __restrict__ X, const int* __restrict__ gid,
    const float* __restrict__ Wc, const float* __restrict__ bc,
    float* __restrict__ out)
{
    __shared__ float part[8][HD];
    __shared__ float shg[HD];
    __shared__ int slo, shi;
    const int g = blockIdx.x;
    const int tid = threadIdx.x;
    const int c = tid & 127;
    const int gr = tid >> 7;            // 8 row-groups
    if (tid == 0) {
        int lo = 0, hi = NN;
        while (lo < hi) { int mid = (lo + hi) >> 1; if (gid[mid] < g) lo = mid + 1; else hi = mid; }
        slo = lo;
        int lo2 = lo; hi = NN;
        while (lo2 < hi) { int mid = (lo2 + hi) >> 1; if (gid[mid] < g + 1) lo2 = mid + 1; else hi = mid; }
        shi = lo2;
    }
    __syncthreads();
    const int lo = slo, hi = shi;
    float acc = 0.f;
    for (int n = lo + gr; n < hi; n += 8) acc += X[(size_t)n * HD + c];
    part[gr][c] = acc;
    __syncthreads();
    if (gr == 0) {
        float s = part[0][c] + part[1][c] + part[2][c] + part[3][c]
                + part[4][c] + part[5][c] + part[6][c] + part[7][c];
        shg[c] = s / fmaxf((float)(hi - lo), 1.f);
    }
    __syncthreads();
    if (tid < NC) {
        float r = bc[tid];
        #pragma unroll
        for (int k = 0; k < HD; ++k) r = fmaf(shg[k], Wc[k * NC + tid], r);
        out[g * NC + tid] = r;
    }
}

extern "C" void kernel_launch(void* const* d_in, const int* in_sizes, int n_in,
                              void* d_out, int out_size, void* d_ws, size_t ws_size,
                              hipStream_t stream) {
    const float* h    = (const float*)d_in[0];
    const int*   src  = (const int*)  d_in[1];
    const int*   dst  = (const int*)  d_in[2];
    const int*   gid  = (const int*)  d_in[3];
    const float* W1   = (const float*)d_in[4];
    const float* al1  = (const float*)d_in[5];
    const float* ar1  = (const float*)d_in[6];
    const float* b1   = (const float*)d_in[7];
    const float* W2   = (const float*)d_in[8];
    const float* al2  = (const float*)d_in[9];
    const float* ar2  = (const float*)d_in[10];
    const float* b2   = (const float*)d_in[11];
    const float* Wc   = (const float*)d_in[12];
    const float* bc   = (const float*)d_in[13];
    float* out = (float*)d_out;

    char* w = (char*)d_ws;
    __half* zh  = (__half*)w; w += (size_t)NN * HD * 2;   // 12.8 MB
    float* xb   = (float*)w;  w += (size_t)NN * HD * 4;   // 25.6 MB
    float* el   = (float*)w;  w += (size_t)NN * NH * 4;
    float* er   = (float*)w;  w += (size_t)NN * NH * 4;
    int*   deg  = (int*)w;    w += (size_t)NN * 4;
    int*   offs = (int*)w;    w += (size_t)(NN + 1) * 4;
    int*   bsum = (int*)w;    w += (size_t)NBLK * 4;
    int*   rank = (int*)w;    w += (size_t)NE * 4;        // 3.2 MB
    int*   csrc = (int*)w;    w += (size_t)NE * 4;        // 3.2 MB

    const int TB = 256;
    const int gE    = (NE + TB - 1) / TB;
    const int gGemm = (NN + GROWS - 1) / GROWS;  // 782
    const int gEdge = (NN * 64 + TB - 1) / TB;   // one wave per dst

    // ---------------- CSR build (dst constant across layers) ----------------
    hipMemsetAsync(deg, 0, (size_t)NN * 4, stream);
    k_deg<<<gE, TB, 0, stream>>>(dst, deg, rank);
    k_scan1<<<NBLK, SCAN_B, 0, stream>>>(deg, offs, bsum);
    k_scan2<<<1, 64, 0, stream>>>(bsum, offs);
    k_scan3<<<NBLK, SCAN_B, 0, stream>>>(offs, bsum);
    k_scatter<<<gE, TB, 0, stream>>>(src, dst, rank, offs, csrc);

    // ---------------- layer 1 ----------------
    k_gemm_attn<<<gGemm, 256, 0, stream>>>(h, W1, al1, ar1, zh, el, er);
    k_edge_gat<<<gEdge, TB, 0, stream>>>(offs, csrc, el, er, zh, b1, xb);

    // ---------------- layer 2 ----------------
    k_gemm_attn<<<gGemm, 256, 0, stream>>>(xb, W2, al2, ar2, zh, el, er);
    k_edge_gat<<<gEdge, TB, 0, stream>>>(offs, csrc, el, er, zh, b2, xb);

    // ---------------- fused pooling + classifier ----------------
    k_pool_classify<<<NG, 1024, 0, stream>>>(xb, gid, Wc, bc, out);
}

// Round 13
// 289.100 us; speedup vs baseline: 6.0132x; 1.0499x over previous
//
#include <hip/hip_runtime.h>
#include <hip/hip_fp16.h>
#include <math.h>

#define NN 50000      // nodes
#define NE 800000     // edges
#define NG 128        // graphs
#define HD 128        // H*D
#define NH 4          // heads
#define NC 10         // classes
#define NEG_SLOPE 0.2f

typedef _Float16 f16x8 __attribute__((ext_vector_type(8)));
typedef float    f32x4 __attribute__((ext_vector_type(4)));

// ---- MFMA fp16 GEMM (x[N,128] @ W[128,128]) fused with el/er logits ----
// (unchanged from round 11 — verified passing, absmax 1.95e-3)
#define GROWS 64
__global__ __launch_bounds__(256, 2) void k_gemm_attn(
    const float* __restrict__ X, const float* __restrict__ W,
    const float* __restrict__ al, const float* __restrict__ ar,
    __half* __restrict__ Zh, float* __restrict__ el, float* __restrict__ er)
{
    __shared__ __align__(16) _Float16 Wp[4][8][64][8];   // 32 KiB
    const int tid = threadIdx.x;
    for (int idx = tid; idx < 128 * 32; idx += 256) {
        int k = idx >> 5, n4 = idx & 31;
        float4 wv = *(const float4*)&W[k * HD + n4 * 4];
        int kt = k >> 5, kin = k & 31;
        int kg = kin >> 3, j = kin & 7;
        #pragma unroll
        for (int q = 0; q < 4; ++q) {
            int n = n4 * 4 + q;
            float v = (q == 0) ? wv.x : (q == 1) ? wv.y : (q == 2) ? wv.z : wv.w;
            Wp[kt][n >> 4][kg * 16 + (n & 15)][j] = (_Float16)v;
        }
    }
    const int w = tid >> 6, l = tid & 63;
    const int l15 = l & 15, lg = l >> 4;
    const int rbase = blockIdx.x * GROWS + w * 16;
    int arow = rbase + l15;
    int arow_c = arow < NN ? arow : NN - 1;
    __syncthreads();

    f32x4 acc[8];
    #pragma unroll
    for (int nt = 0; nt < 8; ++nt) acc[nt] = (f32x4)(0.f);

    #pragma unroll
    for (int kt = 0; kt < 4; ++kt) {
        const float* xp = &X[(size_t)arow_c * HD + kt * 32 + lg * 8];
        float4 x0 = *(const float4*)xp;
        float4 x1 = *(const float4*)(xp + 4);
        f16x8 afrag;
        afrag[0] = (_Float16)x0.x; afrag[1] = (_Float16)x0.y;
        afrag[2] = (_Float16)x0.z; afrag[3] = (_Float16)x0.w;
        afrag[4] = (_Float16)x1.x; afrag[5] = (_Float16)x1.y;
        afrag[6] = (_Float16)x1.z; afrag[7] = (_Float16)x1.w;
        #pragma unroll
        for (int nt = 0; nt < 8; ++nt) {
            f16x8 bfrag = *(const f16x8*)&Wp[kt][nt][l][0];
            acc[nt] = __builtin_amdgcn_mfma_f32_16x16x32_f16(afrag, bfrag, acc[nt], 0, 0, 0);
        }
    }

    float alv[8], arv[8];
    #pragma unroll
    for (int nt = 0; nt < 8; ++nt) {
        alv[nt] = al[nt * 16 + l15];
        arv[nt] = ar[nt * 16 + l15];
    }
    float pl[4][4], pr[4][4];
    #pragma unroll
    for (int j = 0; j < 4; ++j)
        #pragma unroll
        for (int h = 0; h < 4; ++h) {
            pl[j][h] = acc[2*h][j] * alv[2*h] + acc[2*h+1][j] * alv[2*h+1];
            pr[j][h] = acc[2*h][j] * arv[2*h] + acc[2*h+1][j] * arv[2*h+1];
        }
    #pragma unroll
    for (int off = 1; off <= 8; off <<= 1)
        #pragma unroll
        for (int j = 0; j < 4; ++j)
            #pragma unroll
            for (int h = 0; h < 4; ++h) {
                pl[j][h] += __shfl_xor(pl[j][h], off);
                pr[j][h] += __shfl_xor(pr[j][h], off);
            }
    if (l15 == 0) {
        #pragma unroll
        for (int j = 0; j < 4; ++j) {
            int r = rbase + lg * 4 + j;
            if (r < NN) {
                *(float4*)&el[(size_t)r * NH] = make_float4(pl[j][0], pl[j][1], pl[j][2], pl[j][3]);
                *(float4*)&er[(size_t)r * NH] = make_float4(pr[j][0], pr[j][1], pr[j][2], pr[j][3]);
            }
        }
    }
    #pragma unroll
    for (int j = 0; j < 4; ++j) {
        int r = rbase + lg * 4 + j;
        if (r < NN) {
            #pragma unroll
            for (int nt = 0; nt < 8; ++nt)
                Zh[(size_t)r * HD + nt * 16 + l15] = __float2half(acc[nt][j]);
        }
    }
}

// ---------------- CSR build (dst-sorted edge list), once per call ----------------
// x4-vectorized: 4 edges/thread, 4 independent atomics in flight.
// rank = atomicAdd return (any within-segment permutation is valid).
__global__ void k_deg(const int* __restrict__ dst, int* __restrict__ deg,
                      int* __restrict__ rank) {
    int base = (blockIdx.x * blockDim.x + threadIdx.x) * 4;
    if (base + 3 < NE) {
        int4 d4 = *(const int4*)&dst[base];
        int4 r4;
        r4.x = atomicAdd(&deg[d4.x], 1);
        r4.y = atomicAdd(&deg[d4.y], 1);
        r4.z = atomicAdd(&deg[d4.z], 1);
        r4.w = atomicAdd(&deg[d4.w], 1);
        *(int4*)&rank[base] = r4;
    } else {
        for (int t = base; t < NE; ++t) rank[t] = atomicAdd(&deg[dst[t]], 1);
    }
}

#define SCAN_B 1024
#define NBLK ((NN + SCAN_B - 1) / SCAN_B)   // 49

__global__ __launch_bounds__(1024) void k_scan1(const int* __restrict__ deg,
                                                int* __restrict__ offs,
                                                int* __restrict__ bsum)
{
    __shared__ int wsum[16];
    const int tid = threadIdx.x, lane = tid & 63, w = tid >> 6;
    const int i = blockIdx.x * SCAN_B + tid;
    int v = (i < NN) ? deg[i] : 0;
    int x = v;
    #pragma unroll
    for (int off = 1; off < 64; off <<= 1) {
        int t = __shfl_up(x, off);
        if (lane >= off) x += t;
    }
    if (lane == 63) wsum[w] = x;
    __syncthreads();
    if (w == 0 && lane < 16) {
        int t = wsum[lane];
        #pragma unroll
        for (int off = 1; off < 16; off <<= 1) {
            int u = __shfl_up(t, off);
            if (lane >= off) t += u;
        }
        wsum[lane] = t;
    }
    __syncthreads();
    int wbase = (w == 0) ? 0 : wsum[w - 1];
    if (i < NN) offs[i] = wbase + x - v;
    if (tid == 0) bsum[blockIdx.x] = wsum[15];
}

__global__ __launch_bounds__(64) void k_scan2(int* __restrict__ bsum,
                                              int* __restrict__ offs)
{
    const int lane = threadIdx.x;
    int v = (lane < NBLK) ? bsum[lane] : 0;
    int x = v;
    #pragma unroll
    for (int off = 1; off < 64; off <<= 1) {
        int t = __shfl_up(x, off);
        if (lane >= off) x += t;
    }
    if (lane < NBLK) bsum[lane] = x - v;
    if (lane == 63) offs[NN] = x;     // == NE
}

__global__ __launch_bounds__(1024) void k_scan3(int* __restrict__ offs,
                                                const int* __restrict__ bsum)
{
    const int i = blockIdx.x * SCAN_B + threadIdx.x;
    if (i < NN) offs[i] += bsum[blockIdx.x];
}

// atomic-free scatter, x4-vectorized: 4 independent gather+scatter chains.
__global__ void k_scatter(const int* __restrict__ src, const int* __restrict__ dst,
                          const int* __restrict__ rank, const int* __restrict__ offs,
                          int* __restrict__ csrc) {
    int base = (blockIdx.x * blockDim.x + threadIdx.x) * 4;
    if (base + 3 < NE) {
        int4 s4 = *(const int4*)&src[base];
        int4 d4 = *(const int4*)&dst[base];
        int4 r4 = *(const int4*)&rank[base];
        csrc[offs[d4.x] + r4.x] = s4.x;
        csrc[offs[d4.y] + r4.y] = s4.y;
        csrc[offs[d4.z] + r4.z] = s4.z;
        csrc[offs[d4.w] + r4.w] = s4.w;
    } else {
        for (int t = base; t < NE; ++t) csrc[offs[dst[t]] + rank[t]] = src[t];
    }
}

// ---- fused edge softmax + aggregate + finalize: 4 dst nodes per wave ----
// 16 lanes/node, 8 channels/lane (c0 = (lane&15)*8, all in head (lane&15)>>2).
// One VALU stream (exp/fma) serves 4 nodes' edges concurrently -> per-edge
// VALU cost /4; z-row read is 16 lanes x 16B = 256B per edge (same bytes).
__global__ __launch_bounds__(256) void k_edge_gat(
    const int* __restrict__ offs, const int* __restrict__ csrc,
    const float* __restrict__ el, const float* __restrict__ er,
    const __half* __restrict__ Zh, const float* __restrict__ b,
    float* __restrict__ X)
{
    int wave = (int)((blockIdx.x * (unsigned)blockDim.x + threadIdx.x) >> 6);
    int lane = threadIdx.x & 63;
    int sub = lane >> 4;                 // node slot 0..3
    int hl  = lane & 15;                 // lane within node
    int d = wave * 4 + sub;
    if (d >= NN) return;
    const int beg = offs[d], end = offs[d + 1];
    const int c0 = hl * 8;               // 8 channels, within head h
    const int h = hl >> 2;
    const float erd = er[d * NH + h];
    const float4 bb0 = *(const float4*)&b[c0];
    const float4 bb1 = *(const float4*)&b[c0 + 4];

    float sden = 0.f;
    float a0 = 0.f, a1 = 0.f, a2 = 0.f, a3 = 0.f;
    float a4 = 0.f, a5 = 0.f, a6 = 0.f, a7 = 0.f;

    int i = beg;
    for (; i + 1 < end; i += 2) {
        int sA = csrc[i], sB = csrc[i + 1];
        uint4 uA = *(const uint4*)&Zh[(size_t)sA * HD + c0];
        uint4 uB = *(const uint4*)&Zh[(size_t)sB * HD + c0];
        float eA = el[sA * NH + h] + erd;
        float eB = el[sB * NH + h] + erd;
        eA = eA >= 0.f ? eA : NEG_SLOPE * eA;
        eB = eB >= 0.f ? eB : NEG_SLOPE * eB;
        float pA = __expf(eA), pB = __expf(eB);
        sden += pA + pB;
        {
            float2 f0 = __half22float2(*(const __half2*)&uA.x);
            float2 f1 = __half22float2(*(const __half2*)&uA.y);
            float2 f2 = __half22float2(*(const __half2*)&uA.z);
            float2 f3 = __half22float2(*(const __half2*)&uA.w);
            a0 = fmaf(f0.x, pA, a0); a1 = fmaf(f0.y, pA, a1);
            a2 = fmaf(f1.x, pA, a2); a3 = fmaf(f1.y, pA, a3);
            a4 = fmaf(f2.x, pA, a4); a5 = fmaf(f2.y, pA, a5);
            a6 = fmaf(f3.x, pA, a6); a7 = fmaf(f3.y, pA, a7);
        }
        {
            float2 f0 = __half22float2(*(const __half2*)&uB.x);
            float2 f1 = __half22float2(*(const __half2*)&uB.y);
            float2 f2 = __half22float2(*(const __half2*)&uB.z);
            float2 f3 = __half22float2(*(const __half2*)&uB.w);
            a0 = fmaf(f0.x, pB, a0); a1 = fmaf(f0.y, pB, a1);
            a2 = fmaf(f1.x, pB, a2); a3 = fmaf(f1.y, pB, a3);
            a4 = fmaf(f2.x, pB, a4); a5 = fmaf(f2.y, pB, a5);
            a6 = fmaf(f3.x, pB, a6); a7 = fmaf(f3.y, pB, a7);
        }
    }
    if (i < end) {
        int s = csrc[i];
        uint4 u = *(const uint4*)&Zh[(size_t)s * HD + c0];
        float e = el[s * NH + h] + erd;
        e = e >= 0.f ? e : NEG_SLOPE * e;
        float p = __expf(e);
        sden += p;
        float2 f0 = __half22float2(*(const __half2*)&u.x);
        float2 f1 = __half22float2(*(const __half2*)&u.y);
        float2 f2 = __half22float2(*(const __half2*)&u.z);
        float2 f3 = __half22float2(*(const __half2*)&u.w);
        a0 = fmaf(f0.x, p, a0); a1 = fmaf(f0.y, p, a1);
        a2 = fmaf(f1.x, p, a2); a3 = fmaf(f1.y, p, a3);
        a4 = fmaf(f2.x, p, a4); a5 = fmaf(f2.y, p, a5);
        a6 = fmaf(f3.x, p, a6); a7 = fmaf(f3.y, p, a7);
    }
    float inv = (end > beg) ? 1.f / sden : 0.f;
    float4 o0, o1;
    o0.x = fmaxf(fmaf(a0, inv, bb0.x), 0.f);
    o0.y = fmaxf(fmaf(a1, inv, bb0.y), 0.f);
    o0.z = fmaxf(fmaf(a2, inv, bb0.z), 0.f);
    o0.w = fmaxf(fmaf(a3, inv, bb0.w), 0.f);
    o1.x = fmaxf(fmaf(a4, inv, bb1.x), 0.f);
    o1.y = fmaxf(fmaf(a5, inv, bb1.y), 0.f);
    o1.z = fmaxf(fmaf(a6, inv, bb1.z), 0.f);
    o1.w = fmaxf(fmaf(a7, inv, bb1.w), 0.f);
    *(float4*)&X[(size_t)d * HD + c0]     = o0;
    *(float4*)&X[(size_t)d * HD + c0 + 4] = o1;
}

// ---- fused mean-pool + classifier: one 1024-thread block per graph ----
__global__ __launch_bounds__(1024) void k_pool_classify(
    const float* __restrict__ X, const int* __restrict__ gid,
    const float* __restrict__ Wc, const float* __restrict__ bc,
    float* __restrict__ out)
{
    __shared__ float part[8][HD];
    __shared__ float shg[HD];
    __shared__ int slo, shi;
    const int g = blockIdx.x;
    const int tid = threadIdx.x;
    const int c = tid & 127;
    const int gr = tid >> 7;
    if (tid == 0) {
        int lo = 0, hi = NN;
        while (lo < hi) { int mid = (lo + hi) >> 1; if (gid[mid] < g) lo = mid + 1; else hi = mid; }
        slo = lo;
        int lo2 = lo; hi = NN;
        while (lo2 < hi) { int mid = (lo2 + hi) >> 1; if (gid[mid] < g + 1) lo2 = mid + 1; else hi = mid; }
        shi = lo2;
    }
    __syncthreads();
    const int lo = slo, hi = shi;
    float acc = 0.f;
    for (int n = lo + gr; n < hi; n += 8) acc += X[(size_t)n * HD + c];
    part[gr][c] = acc;
    __syncthreads();
    if (gr == 0) {
        float s = part[0][c] + part[1][c] + part[2][c] + part[3][c]
                + part[4][c] + part[5][c] + part[6][c] + part[7][c];
        shg[c] = s / fmaxf((float)(hi - lo), 1.f);
    }
    __syncthreads();
    if (tid < NC) {
        float r = bc[tid];
        #pragma unroll
        for (int k = 0; k < HD; ++k) r = fmaf(shg[k], Wc[k * NC + tid], r);
        out[g * NC + tid] = r;
    }
}

extern "C" void kernel_launch(void* const* d_in, const int* in_sizes, int n_in,
                              void* d_out, int out_size, void* d_ws, size_t ws_size,
                              hipStream_t stream) {
    const float* h    = (const float*)d_in[0];
    const int*   src  = (const int*)  d_in[1];
    const int*   dst  = (const int*)  d_in[2];
    const int*   gid  = (const int*)  d_in[3];
    const float* W1   = (const float*)d_in[4];
    const float* al1  = (const float*)d_in[5];
    const float* ar1  = (const float*)d_in[6];
    const float* b1   = (const float*)d_in[7];
    const float* W2   = (const float*)d_in[8];
    const float* al2  = (const float*)d_in[9];
    const float* ar2  = (const float*)d_in[10];
    const float* b2   = (const float*)d_in[11];
    const float* Wc   = (const float*)d_in[12];
    const float* bc   = (const float*)d_in[13];
    float* out = (float*)d_out;

    char* w = (char*)d_ws;
    __half* zh  = (__half*)w; w += (size_t)NN * HD * 2;   // 12.8 MB
    float* xb   = (float*)w;  w += (size_t)NN * HD * 4;   // 25.6 MB
    float* el   = (float*)w;  w += (size_t)NN * NH * 4;
    float* er   = (float*)w;  w += (size_t)NN * NH * 4;
    int*   deg  = (int*)w;    w += (size_t)NN * 4;
    int*   offs = (int*)w;    w += (size_t)(NN + 1) * 4;
    int*   bsum = (int*)w;    w += (size_t)NBLK * 4;
    int*   rank = (int*)w;    w += (size_t)NE * 4;        // 3.2 MB
    int*   csrc = (int*)w;    w += (size_t)NE * 4;        // 3.2 MB

    const int TB = 256;
    const int gE4   = (NE / 4 + TB - 1) / TB;          // 782 blocks (x4 kernels)
    const int gGemm = (NN + GROWS - 1) / GROWS;        // 782
    const int gEdge = ((NN + 3) / 4 * 64 + TB - 1) / TB;  // 4 dst per wave -> 3125

    // ---------------- CSR build (dst constant across layers) ----------------
    hipMemsetAsync(deg, 0, (size_t)NN * 4, stream);
    k_deg<<<gE4, TB, 0, stream>>>(dst, deg, rank);
    k_scan1<<<NBLK, SCAN_B, 0, stream>>>(deg, offs, bsum);
    k_scan2<<<1, 64, 0, stream>>>(bsum, offs);
    k_scan3<<<NBLK, SCAN_B, 0, stream>>>(offs, bsum);
    k_scatter<<<gE4, TB, 0, stream>>>(src, dst, rank, offs, csrc);

    // ---------------- layer 1 ----------------
    k_gemm_attn<<<gGemm, 256, 0, stream>>>(h, W1, al1, ar1, zh, el, er);
    k_edge_gat<<<gEdge, TB, 0, stream>>>(offs, csrc, el, er, zh, b1, xb);

    // ---------------- layer 2 ----------------
    k_gemm_attn<<<gGemm, 256, 0, stream>>>(xb, W2, al2, ar2, zh, el, er);
    k_edge_gat<<<gEdge, TB, 0, stream>>>(offs, csrc, el, er, zh, b2, xb);

    // ---------------- fused pooling + classifier ----------------
    k_pool_classify<<<NG, 1024, 0, stream>>>(xb, gid, Wc, bc, out);
}

// Round 15
// 281.915 us; speedup vs baseline: 6.1665x; 1.0255x over previous
//
#include <hip/hip_runtime.h>
#include <hip/hip_fp16.h>
#include <math.h>
#include <type_traits>

#define NN 50000      // nodes
#define NE 800000     // edges
#define NG 128        // graphs
#define HD 128        // H*D
#define NH 4          // heads
#define NC 10         // classes
#define NEG_SLOPE 0.2f

typedef _Float16 f16x8 __attribute__((ext_vector_type(8)));
typedef float    f32x4 __attribute__((ext_vector_type(4)));

// ---- MFMA fp16 GEMM (x[N,128] @ W[128,128]) fused with el/er logits ----
// Templated on input type: float (layer 1, casts to fp16 in-register) or
// __half (layer 2, direct 16B fragment load — bit-identical to the old
// fp32->fp16 cast path, so no new error).
#define GROWS 64
template <typename T>
__global__ __launch_bounds__(256, 2) void k_gemm_attn(
    const T* __restrict__ X, const float* __restrict__ W,
    const float* __restrict__ al, const float* __restrict__ ar,
    __half* __restrict__ Zh, float* __restrict__ el, float* __restrict__ er)
{
    __shared__ __align__(16) _Float16 Wp[4][8][64][8];   // 32 KiB
    const int tid = threadIdx.x;
    for (int idx = tid; idx < 128 * 32; idx += 256) {
        int k = idx >> 5, n4 = idx & 31;
        float4 wv = *(const float4*)&W[k * HD + n4 * 4];
        int kt = k >> 5, kin = k & 31;
        int kg = kin >> 3, j = kin & 7;
        #pragma unroll
        for (int q = 0; q < 4; ++q) {
            int n = n4 * 4 + q;
            float v = (q == 0) ? wv.x : (q == 1) ? wv.y : (q == 2) ? wv.z : wv.w;
            Wp[kt][n >> 4][kg * 16 + (n & 15)][j] = (_Float16)v;
        }
    }
    const int w = tid >> 6, l = tid & 63;
    const int l15 = l & 15, lg = l >> 4;
    const int rbase = blockIdx.x * GROWS + w * 16;
    int arow = rbase + l15;
    int arow_c = arow < NN ? arow : NN - 1;
    __syncthreads();

    f32x4 acc[8];
    #pragma unroll
    for (int nt = 0; nt < 8; ++nt) acc[nt] = (f32x4)(0.f);

    #pragma unroll
    for (int kt = 0; kt < 4; ++kt) {
        f16x8 afrag;
        if constexpr (std::is_same<T, __half>::value) {
            afrag = *(const f16x8*)&X[(size_t)arow_c * HD + kt * 32 + lg * 8];
        } else {
            const float* xp = &X[(size_t)arow_c * HD + kt * 32 + lg * 8];
            float4 x0 = *(const float4*)xp;
            float4 x1 = *(const float4*)(xp + 4);
            afrag[0] = (_Float16)x0.x; afrag[1] = (_Float16)x0.y;
            afrag[2] = (_Float16)x0.z; afrag[3] = (_Float16)x0.w;
            afrag[4] = (_Float16)x1.x; afrag[5] = (_Float16)x1.y;
            afrag[6] = (_Float16)x1.z; afrag[7] = (_Float16)x1.w;
        }
        #pragma unroll
        for (int nt = 0; nt < 8; ++nt) {
            f16x8 bfrag = *(const f16x8*)&Wp[kt][nt][l][0];
            acc[nt] = __builtin_amdgcn_mfma_f32_16x16x32_f16(afrag, bfrag, acc[nt], 0, 0, 0);
        }
    }

    float alv[8], arv[8];
    #pragma unroll
    for (int nt = 0; nt < 8; ++nt) {
        alv[nt] = al[nt * 16 + l15];
        arv[nt] = ar[nt * 16 + l15];
    }
    float pl[4][4], pr[4][4];
    #pragma unroll
    for (int j = 0; j < 4; ++j)
        #pragma unroll
        for (int h = 0; h < 4; ++h) {
            pl[j][h] = acc[2*h][j] * alv[2*h] + acc[2*h+1][j] * alv[2*h+1];
            pr[j][h] = acc[2*h][j] * arv[2*h] + acc[2*h+1][j] * arv[2*h+1];
        }
    #pragma unroll
    for (int off = 1; off <= 8; off <<= 1)
        #pragma unroll
        for (int j = 0; j < 4; ++j)
            #pragma unroll
            for (int h = 0; h < 4; ++h) {
                pl[j][h] += __shfl_xor(pl[j][h], off);
                pr[j][h] += __shfl_xor(pr[j][h], off);
            }
    if (l15 == 0) {
        #pragma unroll
        for (int j = 0; j < 4; ++j) {
            int r = rbase + lg * 4 + j;
            if (r < NN) {
                *(float4*)&el[(size_t)r * NH] = make_float4(pl[j][0], pl[j][1], pl[j][2], pl[j][3]);
                *(float4*)&er[(size_t)r * NH] = make_float4(pr[j][0], pr[j][1], pr[j][2], pr[j][3]);
            }
        }
    }
    #pragma unroll
    for (int j = 0; j < 4; ++j) {
        int r = rbase + lg * 4 + j;
        if (r < NN) {
            #pragma unroll
            for (int nt = 0; nt < 8; ++nt)
                Zh[(size_t)r * HD + nt * 16 + l15] = __float2half(acc[nt][j]);
        }
    }
}

// ---------------- CSR build (dst-sorted edge list), once per call ----------------
__global__ void k_deg(const int* __restrict__ dst, int* __restrict__ deg,
                      int* __restrict__ rank) {
    int base = (blockIdx.x * blockDim.x + threadIdx.x) * 4;
    if (base + 3 < NE) {
        int4 d4 = *(const int4*)&dst[base];
        int4 r4;
        r4.x = atomicAdd(&deg[d4.x], 1);
        r4.y = atomicAdd(&deg[d4.y], 1);
        r4.z = atomicAdd(&deg[d4.z], 1);
        r4.w = atomicAdd(&deg[d4.w], 1);
        *(int4*)&rank[base] = r4;
    } else {
        for (int t = base; t < NE; ++t) rank[t] = atomicAdd(&deg[dst[t]], 1);
    }
}

#define SCAN_B 1024
#define NBLK ((NN + SCAN_B - 1) / SCAN_B)   // 49

__global__ __launch_bounds__(1024) void k_scan1(const int* __restrict__ deg,
                                                int* __restrict__ offs,
                                                int* __restrict__ bsum)
{
    __shared__ int wsum[16];
    const int tid = threadIdx.x, lane = tid & 63, w = tid >> 6;
    const int i = blockIdx.x * SCAN_B + tid;
    int v = (i < NN) ? deg[i] : 0;
    int x = v;
    #pragma unroll
    for (int off = 1; off < 64; off <<= 1) {
        int t = __shfl_up(x, off);
        if (lane >= off) x += t;
    }
    if (lane == 63) wsum[w] = x;
    __syncthreads();
    if (w == 0 && lane < 16) {
        int t = wsum[lane];
        #pragma unroll
        for (int off = 1; off < 16; off <<= 1) {
            int u = __shfl_up(t, off);
            if (lane >= off) t += u;
        }
        wsum[lane] = t;
    }
    __syncthreads();
    int wbase = (w == 0) ? 0 : wsum[w - 1];
    if (i < NN) offs[i] = wbase + x - v;
    if (tid == 0) bsum[blockIdx.x] = wsum[15];
}

__global__ __launch_bounds__(64) void k_scan2(int* __restrict__ bsum,
                                              int* __restrict__ offs)
{
    const int lane = threadIdx.x;
    int v = (lane < NBLK) ? bsum[lane] : 0;
    int x = v;
    #pragma unroll
    for (int off = 1; off < 64; off <<= 1) {
        int t = __shfl_up(x, off);
        if (lane >= off) x += t;
    }
    if (lane < NBLK) bsum[lane] = x - v;
    if (lane == 63) offs[NN] = x;     // == NE
}

__global__ __launch_bounds__(1024) void k_scan3(int* __restrict__ offs,
                                                const int* __restrict__ bsum)
{
    const int i = blockIdx.x * SCAN_B + threadIdx.x;
    if (i < NN) offs[i] += bsum[blockIdx.x];
}

__global__ void k_scatter(const int* __restrict__ src, const int* __restrict__ dst,
                          const int* __restrict__ rank, const int* __restrict__ offs,
                          int* __restrict__ csrc) {
    int base = (blockIdx.x * blockDim.x + threadIdx.x) * 4;
    if (base + 3 < NE) {
        int4 s4 = *(const int4*)&src[base];
        int4 d4 = *(const int4*)&dst[base];
        int4 r4 = *(const int4*)&rank[base];
        csrc[offs[d4.x] + r4.x] = s4.x;
        csrc[offs[d4.y] + r4.y] = s4.y;
        csrc[offs[d4.z] + r4.z] = s4.z;
        csrc[offs[d4.w] + r4.w] = s4.w;
    } else {
        for (int t = base; t < NE; ++t) csrc[offs[dst[t]] + rank[t]] = src[t];
    }
}

// ---- fused edge softmax + aggregate + finalize: 4 dst nodes per wave ----
// 16 lanes/node, 8 channels/lane; output stored fp16 (half8 = one uint4).
__global__ __launch_bounds__(256) void k_edge_gat(
    const int* __restrict__ offs, const int* __restrict__ csrc,
    const float* __restrict__ el, const float* __restrict__ er,
    const __half* __restrict__ Zh, const float* __restrict__ b,
    __half* __restrict__ X)
{
    int wave = (int)((blockIdx.x * (unsigned)blockDim.x + threadIdx.x) >> 6);
    int lane = threadIdx.x & 63;
    int sub = lane >> 4;                 // node slot 0..3
    int hl  = lane & 15;                 // lane within node
    int d = wave * 4 + sub;
    if (d >= NN) return;
    const int beg = offs[d], end = offs[d + 1];
    const int c0 = hl * 8;               // 8 channels, within head h
    const int h = hl >> 2;
    const float erd = er[d * NH + h];
    const float4 bb0 = *(const float4*)&b[c0];
    const float4 bb1 = *(const float4*)&b[c0 + 4];

    float sden = 0.f;
    float a0 = 0.f, a1 = 0.f, a2 = 0.f, a3 = 0.f;
    float a4 = 0.f, a5 = 0.f, a6 = 0.f, a7 = 0.f;

    int i = beg;
    for (; i + 1 < end; i += 2) {
        int sA = csrc[i], sB = csrc[i + 1];
        uint4 uA = *(const uint4*)&Zh[(size_t)sA * HD + c0];
        uint4 uB = *(const uint4*)&Zh[(size_t)sB * HD + c0];
        float eA = el[sA * NH + h] + erd;
        float eB = el[sB * NH + h] + erd;
        eA = eA >= 0.f ? eA : NEG_SLOPE * eA;
        eB = eB >= 0.f ? eB : NEG_SLOPE * eB;
        float pA = __expf(eA), pB = __expf(eB);
        sden += pA + pB;
        {
            float2 f0 = __half22float2(*(const __half2*)&uA.x);
            float2 f1 = __half22float2(*(const __half2*)&uA.y);
            float2 f2 = __half22float2(*(const __half2*)&uA.z);
            float2 f3 = __half22float2(*(const __half2*)&uA.w);
            a0 = fmaf(f0.x, pA, a0); a1 = fmaf(f0.y, pA, a1);
            a2 = fmaf(f1.x, pA, a2); a3 = fmaf(f1.y, pA, a3);
            a4 = fmaf(f2.x, pA, a4); a5 = fmaf(f2.y, pA, a5);
            a6 = fmaf(f3.x, pA, a6); a7 = fmaf(f3.y, pA, a7);
        }
        {
            float2 f0 = __half22float2(*(const __half2*)&uB.x);
            float2 f1 = __half22float2(*(const __half2*)&uB.y);
            float2 f2 = __half22float2(*(const __half2*)&uB.z);
            float2 f3 = __half22float2(*(const __half2*)&uB.w);
            a0 = fmaf(f0.x, pB, a0); a1 = fmaf(f0.y, pB, a1);
            a2 = fmaf(f1.x, pB, a2); a3 = fmaf(f1.y, pB, a3);
            a4 = fmaf(f2.x, pB, a4); a5 = fmaf(f2.y, pB, a5);
            a6 = fmaf(f3.x, pB, a6); a7 = fmaf(f3.y, pB, a7);
        }
    }
    if (i < end) {
        int s = csrc[i];
        uint4 u = *(const uint4*)&Zh[(size_t)s * HD + c0];
        float e = el[s * NH + h] + erd;
        e = e >= 0.f ? e : NEG_SLOPE * e;
        float p = __expf(e);
        sden += p;
        float2 f0 = __half22float2(*(const __half2*)&u.x);
        float2 f1 = __half22float2(*(const __half2*)&u.y);
        float2 f2 = __half22float2(*(const __half2*)&u.z);
        float2 f3 = __half22float2(*(const __half2*)&u.w);
        a0 = fmaf(f0.x, p, a0); a1 = fmaf(f0.y, p, a1);
        a2 = fmaf(f1.x, p, a2); a3 = fmaf(f1.y, p, a3);
        a4 = fmaf(f2.x, p, a4); a5 = fmaf(f2.y, p, a5);
        a6 = fmaf(f3.x, p, a6); a7 = fmaf(f3.y, p, a7);
    }
    float inv = (end > beg) ? 1.f / sden : 0.f;
    __half2 h0 = __floats2half2_rn(fmaxf(fmaf(a0, inv, bb0.x), 0.f),
                                   fmaxf(fmaf(a1, inv, bb0.y), 0.f));
    __half2 h1 = __floats2half2_rn(fmaxf(fmaf(a2, inv, bb0.z), 0.f),
                                   fmaxf(fmaf(a3, inv, bb0.w), 0.f));
    __half2 h2 = __floats2half2_rn(fmaxf(fmaf(a4, inv, bb1.x), 0.f),
                                   fmaxf(fmaf(a5, inv, bb1.y), 0.f));
    __half2 h3 = __floats2half2_rn(fmaxf(fmaf(a6, inv, bb1.z), 0.f),
                                   fmaxf(fmaf(a7, inv, bb1.w), 0.f));
    uint4 st;
    st.x = *(unsigned*)&h0; st.y = *(unsigned*)&h1;
    st.z = *(unsigned*)&h2; st.w = *(unsigned*)&h3;
    *(uint4*)&X[(size_t)d * HD + c0] = st;
}

// ---- fused mean-pool + classifier: one 1024-thread block per graph ----
// fp16 input, half2 loads: 2 channels/lane, 16 row-groups.
__global__ __launch_bounds__(1024) void k_pool_classify(
    const __half* __restrict__ X, const int* __restrict__ gid,
    const float* __restrict__ Wc, const float* __restrict__ bc,
    float* __restrict__ out)
{
    __shared__ float part[16][HD];   // 8 KiB
    __shared__ float shg[HD];
    __shared__ int slo, shi;
    const int g = blockIdx.x;
    const int tid = threadIdx.x;
    const int cp = tid & 63;            // channel pair index -> channels 2cp, 2cp+1
    const int gr = tid >> 6;            // 16 row-groups
    if (tid == 0) {
        int lo = 0, hi = NN;
        while (lo < hi) { int mid = (lo + hi) >> 1; if (gid[mid] < g) lo = mid + 1; else hi = mid; }
        slo = lo;
        int lo2 = lo; hi = NN;
        while (lo2 < hi) { int mid = (lo2 + hi) >> 1; if (gid[mid] < g + 1) lo2 = mid + 1; else hi = mid; }
        shi = lo2;
    }
    __syncthreads();
    const int lo = slo, hi = shi;
    float a0 = 0.f, a1 = 0.f;
    for (int n = lo + gr; n < hi; n += 16) {
        __half2 v = *(const __half2*)&X[(size_t)n * HD + cp * 2];
        float2 f = __half22float2(v);
        a0 += f.x; a1 += f.y;
    }
    part[gr][cp * 2]     = a0;
    part[gr][cp * 2 + 1] = a1;
    __syncthreads();
    if (tid < HD) {
        float s = 0.f;
        #pragma unroll
        for (int r = 0; r < 16; ++r) s += part[r][tid];
        shg[tid] = s / fmaxf((float)(hi - lo), 1.f);
    }
    __syncthreads();
    if (tid < NC) {
        float r = bc[tid];
        #pragma unroll
        for (int k = 0; k < HD; ++k) r = fmaf(shg[k], Wc[k * NC + tid], r);
        out[g * NC + tid] = r;
    }
}

extern "C" void kernel_launch(void* const* d_in, const int* in_sizes, int n_in,
                              void* d_out, int out_size, void* d_ws, size_t ws_size,
                              hipStream_t stream) {
    const float* h    = (const float*)d_in[0];
    const int*   src  = (const int*)  d_in[1];
    const int*   dst  = (const int*)  d_in[2];
    const int*   gid  = (const int*)  d_in[3];
    const float* W1   = (const float*)d_in[4];
    const float* al1  = (const float*)d_in[5];
    const float* ar1  = (const float*)d_in[6];
    const float* b1   = (const float*)d_in[7];
    const float* W2   = (const float*)d_in[8];
    const float* al2  = (const float*)d_in[9];
    const float* ar2  = (const float*)d_in[10];
    const float* b2   = (const float*)d_in[11];
    const float* Wc   = (const float*)d_in[12];
    const float* bc   = (const float*)d_in[13];
    float* out = (float*)d_out;

    char* w = (char*)d_ws;
    __half* zh  = (__half*)w; w += (size_t)NN * HD * 2;   // 12.8 MB
    __half* xb  = (__half*)w; w += (size_t)NN * HD * 2;   // 12.8 MB
    float* el   = (float*)w;  w += (size_t)NN * NH * 4;
    float* er   = (float*)w;  w += (size_t)NN * NH * 4;
    int*   deg  = (int*)w;    w += (size_t)NN * 4;
    int*   offs = (int*)w;    w += (size_t)(NN + 1) * 4;
    int*   bsum = (int*)w;    w += (size_t)NBLK * 4;
    int*   rank = (int*)w;    w += (size_t)NE * 4;        // 3.2 MB
    int*   csrc = (int*)w;    w += (size_t)NE * 4;        // 3.2 MB

    const int TB = 256;
    const int gE4   = (NE / 4 + TB - 1) / TB;             // 782
    const int gGemm = (NN + GROWS - 1) / GROWS;           // 782
    const int gEdge = ((NN + 3) / 4 * 64 + TB - 1) / TB;  // 3125

    // ---------------- CSR build (dst constant across layers) ----------------
    hipMemsetAsync(deg, 0, (size_t)NN * 4, stream);
    k_deg<<<gE4, TB, 0, stream>>>(dst, deg, rank);
    k_scan1<<<NBLK, SCAN_B, 0, stream>>>(deg, offs, bsum);
    k_scan2<<<1, 64, 0, stream>>>(bsum, offs);
    k_scan3<<<NBLK, SCAN_B, 0, stream>>>(offs, bsum);
    k_scatter<<<gE4, TB, 0, stream>>>(src, dst, rank, offs, csrc);

    // ---------------- layer 1 ----------------
    k_gemm_attn<float><<<gGemm, 256, 0, stream>>>(h, W1, al1, ar1, zh, el, er);
    k_edge_gat<<<gEdge, TB, 0, stream>>>(offs, csrc, el, er, zh, b1, xb);

    // ---------------- layer 2 ----------------
    k_gemm_attn<__half><<<gGemm, 256, 0, stream>>>(xb, W2, al2, ar2, zh, el, er);
    k_edge_gat<<<gEdge, TB, 0, stream>>>(offs, csrc, el, er, zh, b2, xb);

    // ---------------- fused pooling + classifier ----------------
    k_pool_classify<<<NG, 1024, 0, stream>>>(xb, gid, Wc, bc, out);
}